// Round 1
// baseline (203.192 us; speedup 1.0000x reference)
//
#include <hip/hip_runtime.h>

// ---------------------------------------------------------------------------
// StateBank: g = W_out @ scan(W_in @ u), restructured as
//   M_k = W_out_k @ W_in_k  (composite, k=0..3, each 1024x1024)
//   Y[b,t,(k,d)] = sum_d' M_k[d,d'] u[b,t,d']       (one 8192x4096x1024 GEMM)
//   z_k[b,t,d] = decay_k z_k[b,t-1,d] + Y[..]       (chunked parallel scan)
//   g[b,t,d] = b_out[d] + sum_k z_k + closed-form b_in/s0 terms
//   s_last[b,k,d] = decay^T s0 + W_in_k @ v_k[b] + b_in geom term,
//     v_k[b,d'] = sum_t decay^{T-1-t} u[b,t,d']
// ---------------------------------------------------------------------------

#define Bb 4
#define Tt 2048
#define Dd 1024
#define Kk 4
#define BT (Bb*Tt)          // 8192
#define Ee (Kk*Dd)          // 4096
#define NCH 32              // scan chunks
#define LCH 64              // chunk length (NCH*LCH = T)

typedef __bf16 bf16x8 __attribute__((ext_vector_type(8)));
typedef float  f32x4  __attribute__((ext_vector_type(4)));

__device__ __forceinline__ float bf2f(ushort u){
  union { unsigned int i; float f; } x; x.i = ((unsigned int)u) << 16; return x.f;
}
__device__ __forceinline__ ushort f2bf(float f){
  union { unsigned int i; float f; } x; x.f = f;
  unsigned int i = x.i;
  return (ushort)((i + 0x7FFFu + ((i >> 16) & 1u)) >> 16);   // RNE
}
__device__ __forceinline__ float sigm(float x){ return 1.0f / (1.0f + expf(-x)); }

// ---------------- convert f32 -> bf16 (vectorized) ----------------
__global__ __launch_bounds__(256) void k_f2bf4(const float4* __restrict__ in,
                                               ushort4* __restrict__ out, int n4){
  int i = blockIdx.x * 256 + threadIdx.x;
  if (i < n4){
    float4 v = in[i];
    ushort4 o; o.x = f2bf(v.x); o.y = f2bf(v.y); o.z = f2bf(v.z); o.w = f2bf(v.w);
    out[i] = o;
  }
}

// ---------------- transpose W_in (4096x1024 f32) -> WinT (1024x4096 bf16) ---
__global__ __launch_bounds__(256) void k_transpose(const float* __restrict__ in,
                                                   ushort* __restrict__ out){
  __shared__ float tile[32][33];
  int tx = threadIdx.x, ty = threadIdx.y;          // 32 x 8
  int c0 = blockIdx.x * 32, r0 = blockIdx.y * 32;  // cols of in, rows of in
  #pragma unroll
  for (int j = 0; j < 4; ++j)
    tile[ty + j*8][tx] = in[(size_t)(r0 + ty + j*8) * Dd + c0 + tx];
  __syncthreads();
  #pragma unroll
  for (int j = 0; j < 4; ++j)
    out[(size_t)(c0 + ty + j*8) * Ee + r0 + tx] = f2bf(tile[tx][ty + j*8]);
}

// ---------------- NT GEMM: C[i,j] = sum_l A[i,l]*B[j,l], bf16 in/out --------
// 128x128 tile, BK=32, 4 waves (2x2), 16x16x32 MFMA, global_load_lds width 16.
__global__ __launch_bounds__(256) void gemm_nt(const ushort* __restrict__ A,
                                               const ushort* __restrict__ B,
                                               ushort* __restrict__ C,
                                               int Kred, int lda, int ldb, int ldc,
                                               long aBatch, long bBatch, long cBatch){
  __shared__ ushort As[128 * 32];  // 8 KB
  __shared__ ushort Bs[128 * 32];  // 8 KB
  A += (long)blockIdx.z * aBatch;
  B += (long)blockIdx.z * bBatch;
  C += (long)blockIdx.z * cBatch;
  const int tid  = threadIdx.x;
  const int lane = tid & 63;
  const int w    = tid >> 6;
  const int wr   = w >> 1, wc = w & 1;
  const int rowBase = blockIdx.x * 128;
  const int colBase = blockIdx.y * 128;

  f32x4 acc[4][4] = {};

  const int krow = (lane >> 4) * 8;   // k-offset within 32
  const int rsel = lane & 15;

  for (int kk = 0; kk < Kred; kk += 32){
    __syncthreads();   // previous tile fully consumed before overwrite
    #pragma unroll
    for (int i = 0; i < 2; ++i){
      int c  = i * 256 + tid;          // 16B chunk id, 512 chunks per tile
      int r  = c >> 2;
      int c8 = (c & 3) * 8;
      const ushort* ga = A + (size_t)(rowBase + r) * lda + kk + c8;
      const ushort* gb = B + (size_t)(colBase + r) * ldb + kk + c8;
      __builtin_amdgcn_global_load_lds((const __attribute__((address_space(1))) void*)ga,
                                       (__attribute__((address_space(3))) void*)&As[c * 8],
                                       16, 0, 0);
      __builtin_amdgcn_global_load_lds((const __attribute__((address_space(1))) void*)gb,
                                       (__attribute__((address_space(3))) void*)&Bs[c * 8],
                                       16, 0, 0);
    }
    asm volatile("s_waitcnt vmcnt(0)" ::: "memory");
    __syncthreads();

    bf16x8 Af[4], Bf[4];
    #pragma unroll
    for (int mi = 0; mi < 4; ++mi)
      Af[mi] = *(const bf16x8*)&As[(wr*64 + mi*16 + rsel) * 32 + krow];
    #pragma unroll
    for (int ni = 0; ni < 4; ++ni)
      Bf[ni] = *(const bf16x8*)&Bs[(wc*64 + ni*16 + rsel) * 32 + krow];
    #pragma unroll
    for (int mi = 0; mi < 4; ++mi)
      #pragma unroll
      for (int ni = 0; ni < 4; ++ni)
        acc[mi][ni] = __builtin_amdgcn_mfma_f32_16x16x32_bf16(Af[mi], Bf[ni], acc[mi][ni], 0, 0, 0);
  }

  #pragma unroll
  for (int mi = 0; mi < 4; ++mi){
    #pragma unroll
    for (int ni = 0; ni < 4; ++ni){
      int r0 = rowBase + wr*64 + mi*16 + (lane >> 4) * 4;
      int c0 = colBase + wc*64 + ni*16 + (lane & 15);
      #pragma unroll
      for (int q = 0; q < 4; ++q)
        C[(size_t)(r0 + q) * ldc + c0] = f2bf(acc[mi][ni][q]);
    }
  }
}

// ---------------- wave-per-output dot kernels (fp32) ------------------------
// z0[b,k,d] = sum_d'' W_out[d, k*D+d''] * s0[b,k,d'']
__global__ __launch_bounds__(256) void k_z0(const float* __restrict__ Wout,
                                            const float* __restrict__ s0,
                                            float* __restrict__ z0){
  int gid  = blockIdx.x * 4 + (threadIdx.x >> 6);   // 0..16383 = (b*K+k)*D+d
  int lane = threadIdx.x & 63;
  int d = gid & 1023, k = (gid >> 10) & 3, b = gid >> 12;
  const float* wrow = Wout + (size_t)d * Ee + k * Dd;
  const float* sv   = s0 + ((size_t)(b*Kk + k) << 10);
  float s = 0.f;
  #pragma unroll
  for (int j = 0; j < 16; ++j) s += wrow[lane + j*64] * sv[lane + j*64];
  for (int off = 32; off; off >>= 1) s += __shfl_down(s, off);
  if (lane == 0) z0[gid] = s;
}

// cterm[k,d] = sum_j W_out[d, k*D+j] * b_in[k*D+j]
__global__ __launch_bounds__(256) void k_cterm(const float* __restrict__ Wout,
                                               const float* __restrict__ b_in,
                                               float* __restrict__ cterm){
  int gid  = blockIdx.x * 4 + (threadIdx.x >> 6);   // 0..4095 = k*D+d
  int lane = threadIdx.x & 63;
  int d = gid & 1023, k = gid >> 10;
  const float* wrow = Wout + (size_t)d * Ee + k * Dd;
  const float* bv   = b_in + k * Dd;
  float s = 0.f;
  #pragma unroll
  for (int j = 0; j < 16; ++j) s += wrow[lane + j*64] * bv[lane + j*64];
  for (int off = 32; off; off >>= 1) s += __shfl_down(s, off);
  if (lane == 0) cterm[gid] = s;
}

// ---------------- scan pass A: per-chunk carries ----------------------------
__global__ __launch_bounds__(256) void k_scanA(const ushort* __restrict__ Y,
                                               const float* __restrict__ dlog,
                                               float* __restrict__ carry){
  int x = blockIdx.x;                    // (b*K+k)*NCH + c, 512 total
  int d = blockIdx.y * 256 + threadIdx.x;
  int c = x & 31, k = (x >> 5) & 3, b = x >> 7;
  float p = sigm(dlog[k]);
  float acc = 0.f;
  size_t base = ((size_t)(b*Tt + c*LCH)) * Ee + k * Dd + d;
  for (int i = 0; i < LCH; ++i){ acc = p * acc + bf2f(Y[base]); base += Ee; }
  carry[(size_t)x * Dd + d] = acc;
}

// ---------------- scan pass 2: cross-chunk exclusive scan -------------------
__global__ __launch_bounds__(256) void k_scanInc(const float* __restrict__ carry,
                                                 const float* __restrict__ z0,
                                                 const float* __restrict__ dlog,
                                                 float* __restrict__ incoming){
  int idx = blockIdx.x * 256 + threadIdx.x;   // 16384 = (b*K+k)*D + d
  int k = (idx >> 10) & 3;
  int bk = idx >> 10, d = idx & 1023;
  float p  = sigm(dlog[k]);
  float dL = powf(p, (float)LCH);
  float inc = z0[idx];
  for (int c = 0; c < NCH; ++c){
    size_t o = ((size_t)(bk * NCH + c)) * Dd + d;
    incoming[o] = inc;
    inc = dL * inc + carry[o];
  }
}

// ---------------- scan pass B: apply + sum over k + bias -> g ---------------
__global__ __launch_bounds__(256) void k_scanB(const ushort* __restrict__ Y,
                                               const float* __restrict__ incoming,
                                               const float* __restrict__ dlog,
                                               const float* __restrict__ b_out,
                                               const float* __restrict__ cterm,
                                               float* __restrict__ g){
  int x = blockIdx.x;                    // b*NCH + c, 128 total
  int d = blockIdx.y * 256 + threadIdx.x;
  int c = x & 31, b = x >> 5;
  float p[4], z[4], ct[4], pw[4];
  #pragma unroll
  for (int k = 0; k < 4; ++k){
    p[k]  = sigm(dlog[k]);
    z[k]  = incoming[((size_t)(((b*Kk + k))*NCH + c)) * Dd + d];
    float omp = fmaxf(1.0f - p[k], 1e-30f);
    ct[k] = cterm[k * Dd + d] / omp;
    pw[k] = powf(p[k], (float)(c * LCH + 1));
  }
  float bo = b_out[d];
  size_t ybase = ((size_t)(b*Tt + c*LCH)) * Ee + d;
  size_t gbase = ((size_t)(b*Tt + c*LCH)) * Dd + d;
  for (int i = 0; i < LCH; ++i){
    float acc = bo;
    #pragma unroll
    for (int k = 0; k < 4; ++k){
      z[k] = p[k] * z[k] + bf2f(Y[ybase + (size_t)k * Dd]);
      acc += z[k] + ct[k] * (1.0f - pw[k]);
      pw[k] *= p[k];
    }
    g[gbase] = acc;
    ybase += Ee; gbase += Dd;
  }
}

// ---------------- v path: weighted time reduction of u ----------------------
__global__ __launch_bounds__(256) void k_vpart(const float* __restrict__ u,
                                               const float* __restrict__ dlog,
                                               float* __restrict__ vpart){
  int x = blockIdx.x;                    // b*NCH + c
  int d = blockIdx.y * 256 + threadIdx.x;
  int c = x & 31, b = x >> 5;
  float p[4], a[4] = {0.f, 0.f, 0.f, 0.f};
  #pragma unroll
  for (int k = 0; k < 4; ++k) p[k] = sigm(dlog[k]);
  size_t ub = ((size_t)(b*Tt + c*LCH)) * Dd + d;
  for (int i = 0; i < LCH; ++i){
    float uv = u[ub];
    #pragma unroll
    for (int k = 0; k < 4; ++k) a[k] = p[k] * a[k] + uv;
    ub += Dd;
  }
  #pragma unroll
  for (int k = 0; k < 4; ++k)
    vpart[(((size_t)x) * Kk + k) * Dd + d] = a[k];
}

__global__ __launch_bounds__(256) void k_vcomb(const float* __restrict__ vpart,
                                               const float* __restrict__ dlog,
                                               float* __restrict__ vfull){
  int idx = blockIdx.x * 256 + threadIdx.x;   // 16384 = (b*K+k)*D + d'
  int k = (idx >> 10) & 3, b = idx >> 12, d = idx & 1023;
  float p  = sigm(dlog[k]);
  float dL = powf(p, (float)LCH);
  float v = 0.f;
  for (int c = 0; c < NCH; ++c)
    v = dL * v + vpart[(((size_t)(b*NCH + c)) * Kk + k) * Dd + d];
  vfull[idx] = v;
}

// s_last[b,k,d] = p^T s0 + sum_d' W_in[k*D+d, d'] v_k[b,d'] + b_in geom term
__global__ __launch_bounds__(256) void k_slast(const float* __restrict__ W_in,
                                               const float* __restrict__ vfull,
                                               const float* __restrict__ s0,
                                               const float* __restrict__ b_in,
                                               const float* __restrict__ dlog,
                                               float* __restrict__ out){
  int gid  = blockIdx.x * 4 + (threadIdx.x >> 6);   // (b*K+k)*D + d
  int lane = threadIdx.x & 63;
  int d = gid & 1023, k = (gid >> 10) & 3, b = gid >> 12;
  const float* wrow = W_in + (size_t)(k*Dd + d) * Dd;
  const float* vv   = vfull + ((size_t)(b*Kk + k) << 10);
  float s = 0.f;
  #pragma unroll
  for (int j = 0; j < 16; ++j) s += wrow[lane + j*64] * vv[lane + j*64];
  for (int off = 32; off; off >>= 1) s += __shfl_down(s, off);
  if (lane == 0){
    float p  = sigm(dlog[k]);
    float pT = powf(p, (float)Tt);
    float omp = 1.0f - p;
    float geo = (omp < 1e-12f) ? (float)Tt : (1.0f - pT) / omp;
    out[gid] = pT * s0[gid] + s + b_in[k*Dd + d] * geo;
  }
}

// ---------------------------------------------------------------------------
extern "C" void kernel_launch(void* const* d_in, const int* in_sizes, int n_in,
                              void* d_out, int out_size, void* d_ws, size_t ws_size,
                              hipStream_t stream){
  const float* u     = (const float*)d_in[0];
  const float* s0    = (const float*)d_in[1];
  const float* W_in  = (const float*)d_in[2];
  const float* b_in  = (const float*)d_in[3];
  const float* W_out = (const float*)d_in[4];
  const float* b_out = (const float*)d_in[5];
  const float* dlog  = (const float*)d_in[6];

  float* g_out     = (float*)d_out;                      // B*T*D
  float* slast_out = g_out + (size_t)BT * Dd;            // B*K*D

  // workspace layout (bytes)
  char* ws = (char*)d_ws;
  if (ws_size < 115490816ull) return;
  ushort* U_bf    = (ushort*)(ws);                       // 16 MB
  ushort* WinT    = (ushort*)(ws + 16777216);            //  8 MB
  ushort* Wout_bf = (ushort*)(ws + 25165824);            //  8 MB
  ushort* Mcat    = (ushort*)(ws + 33554432);            //  8 MB
  ushort* Y       = (ushort*)(ws + 41943040);            // 64 MB
  float*  carry   = (float*)(ws + 109051904);            //  2 MB
  float*  incoming= (float*)(ws + 111149056);            //  2 MB
  float*  z0buf   = (float*)(ws + 113246208);            // 64 KB
  float*  cterm   = (float*)(ws + 113311744);            // 16 KB
  float*  vpart   = (float*)(ws + 113328128);            //  2 MB
  float*  vfull   = (float*)(ws + 115425280);            // 64 KB

  // converts
  k_f2bf4<<<8192, 256, 0, stream>>>((const float4*)u,     (ushort4*)U_bf,    BT*Dd/4);
  k_f2bf4<<<4096, 256, 0, stream>>>((const float4*)W_out, (ushort4*)Wout_bf, Dd*Ee/4);
  k_transpose<<<dim3(32, 128), dim3(32, 8), 0, stream>>>(W_in, WinT);

  // Mcat[(k,d), d'] = sum_j Wout[d, kD+j] * WinT[d', kD+j]  (4 batched NT GEMMs)
  gemm_nt<<<dim3(8, 8, 4), 256, 0, stream>>>(Wout_bf, WinT, Mcat,
                                             1024, Ee, Ee, Dd,
                                             1024L, 1024L, 1048576L);
  // Y[bt, (k,d)] = sum_d' U[bt, d'] * Mcat[(k,d), d']
  gemm_nt<<<dim3(64, 32, 1), 256, 0, stream>>>(U_bf, Mcat, Y,
                                               1024, Dd, Dd, Ee,
                                               0L, 0L, 0L);

  // scan-init terms
  k_z0<<<4096, 256, 0, stream>>>(W_out, s0, z0buf);
  k_cterm<<<1024, 256, 0, stream>>>(W_out, b_in, cterm);

  // chunked scan over t
  k_scanA<<<dim3(512, 4), 256, 0, stream>>>(Y, dlog, carry);
  k_scanInc<<<64, 256, 0, stream>>>(carry, z0buf, dlog, incoming);
  k_scanB<<<dim3(128, 4), 256, 0, stream>>>(Y, incoming, dlog, b_out, cterm, g_out);

  // s_last path
  k_vpart<<<dim3(128, 4), 256, 0, stream>>>(u, dlog, vpart);
  k_vcomb<<<64, 256, 0, stream>>>(vpart, dlog, vfull);
  k_slast<<<4096, 256, 0, stream>>>(W_in, vfull, s0, b_in, dlog, slast_out);
}

// Round 4
// 182.601 us; speedup vs baseline: 1.1128x; 1.1128x over previous
//
#include <hip/hip_runtime.h>

// ---------------------------------------------------------------------------
// StateBank: g = W_out @ scan(W_in @ u), restructured as
//   M_k = W_out_k @ W_in_k  (composite, k=0..3, each 1024x1024)
//   Y[b,t,(k,d)] = sum_d' M_k[d,d'] u[b,t,d']       (one 8192x4096x1024 GEMM)
//   z_k[b,t,d] = decay_k z_k[b,t-1,d] + Y[..]       (chunked parallel scan)
//   g[b,t,d] = b_out[d] + sum_k z_k + closed-form b_in/s0 terms
//   s_last[b,k,d] = decay^T s0 + W_in_k @ v_k[b] + b_in geom term
// Big GEMM: 256x256 tile, BK=64, 8 waves, 8-phase schedule with counted
// vmcnt(6) (T3+T4), LDS XOR swizzle (T2), setprio (T5), XCD swizzle (T1).
// ---------------------------------------------------------------------------

#define Bb 4
#define Tt 2048
#define Dd 1024
#define Kk 4
#define BT (Bb*Tt)          // 8192
#define Ee (Kk*Dd)          // 4096
#define NCH 32              // scan chunks
#define LCH 64              // chunk length (NCH*LCH = T)

typedef __bf16 bf16x8 __attribute__((ext_vector_type(8)));
typedef float  f32x4  __attribute__((ext_vector_type(4)));

__device__ __forceinline__ float bf2f(ushort u){
  union { unsigned int i; float f; } x; x.i = ((unsigned int)u) << 16; return x.f;
}
__device__ __forceinline__ ushort f2bf(float f){
  union { unsigned int i; float f; } x; x.f = f;
  unsigned int i = x.i;
  return (ushort)((i + 0x7FFFu + ((i >> 16) & 1u)) >> 16);   // RNE
}
__device__ __forceinline__ float sigm(float x){ return 1.0f / (1.0f + expf(-x)); }

// ---------------- convert f32 -> bf16 (vectorized) ----------------
__global__ __launch_bounds__(256) void k_f2bf4(const float4* __restrict__ in,
                                               ushort4* __restrict__ out, int n4){
  int i = blockIdx.x * 256 + threadIdx.x;
  if (i < n4){
    float4 v = in[i];
    ushort4 o; o.x = f2bf(v.x); o.y = f2bf(v.y); o.z = f2bf(v.z); o.w = f2bf(v.w);
    out[i] = o;
  }
}

// ---------------- transpose W_in (4096x1024 f32) -> WinT (1024x4096 bf16) ---
__global__ __launch_bounds__(256) void k_transpose(const float* __restrict__ in,
                                                   ushort* __restrict__ out){
  __shared__ float tile[32][33];
  int tx = threadIdx.x, ty = threadIdx.y;          // 32 x 8
  int c0 = blockIdx.x * 32, r0 = blockIdx.y * 32;  // cols of in, rows of in
  #pragma unroll
  for (int j = 0; j < 4; ++j)
    tile[ty + j*8][tx] = in[(size_t)(r0 + ty + j*8) * Dd + c0 + tx];
  __syncthreads();
  #pragma unroll
  for (int j = 0; j < 4; ++j)
    out[(size_t)(c0 + ty + j*8) * Ee + r0 + tx] = f2bf(tile[tx][ty + j*8]);
}

// ---------------- small NT GEMM (m97 structure) for Mcat --------------------
__global__ __launch_bounds__(256) void gemm_nt(const ushort* __restrict__ A,
                                               const ushort* __restrict__ B,
                                               ushort* __restrict__ C,
                                               int Kred, int lda, int ldb, int ldc,
                                               long aBatch, long bBatch, long cBatch){
  __shared__ ushort As[128 * 32];
  __shared__ ushort Bs[128 * 32];
  A += (long)blockIdx.z * aBatch;
  B += (long)blockIdx.z * bBatch;
  C += (long)blockIdx.z * cBatch;
  const int tid  = threadIdx.x;
  const int lane = tid & 63;
  const int w    = tid >> 6;
  const int wr   = w >> 1, wc = w & 1;
  const int rowBase = blockIdx.x * 128;
  const int colBase = blockIdx.y * 128;

  f32x4 acc[4][4] = {};
  const int krow = (lane >> 4) * 8;
  const int rsel = lane & 15;

  for (int kk = 0; kk < Kred; kk += 32){
    __syncthreads();
    #pragma unroll
    for (int i = 0; i < 2; ++i){
      int c  = i * 256 + tid;
      int r  = c >> 2;
      int c8 = (c & 3) * 8;
      const ushort* ga = A + (size_t)(rowBase + r) * lda + kk + c8;
      const ushort* gb = B + (size_t)(colBase + r) * ldb + kk + c8;
      __builtin_amdgcn_global_load_lds((const __attribute__((address_space(1))) void*)ga,
                                       (__attribute__((address_space(3))) void*)&As[c * 8],
                                       16, 0, 0);
      __builtin_amdgcn_global_load_lds((const __attribute__((address_space(1))) void*)gb,
                                       (__attribute__((address_space(3))) void*)&Bs[c * 8],
                                       16, 0, 0);
    }
    asm volatile("s_waitcnt vmcnt(0)" ::: "memory");
    __syncthreads();

    bf16x8 Af[4], Bf[4];
    #pragma unroll
    for (int mi = 0; mi < 4; ++mi)
      Af[mi] = *(const bf16x8*)&As[(wr*64 + mi*16 + rsel) * 32 + krow];
    #pragma unroll
    for (int ni = 0; ni < 4; ++ni)
      Bf[ni] = *(const bf16x8*)&Bs[(wc*64 + ni*16 + rsel) * 32 + krow];
    #pragma unroll
    for (int mi = 0; mi < 4; ++mi)
      #pragma unroll
      for (int ni = 0; ni < 4; ++ni)
        acc[mi][ni] = __builtin_amdgcn_mfma_f32_16x16x32_bf16(Af[mi], Bf[ni], acc[mi][ni], 0, 0, 0);
  }

  #pragma unroll
  for (int mi = 0; mi < 4; ++mi){
    #pragma unroll
    for (int ni = 0; ni < 4; ++ni){
      int r0 = rowBase + wr*64 + mi*16 + (lane >> 4) * 4;
      int c0 = colBase + wc*64 + ni*16 + (lane & 15);
      #pragma unroll
      for (int q = 0; q < 4; ++q)
        C[(size_t)(r0 + q) * ldc + c0] = f2bf(acc[mi][ni][q]);
    }
  }
}

// ---------------- big GEMM: Y[8192,4096] = U[8192,1024] @ Mcat[4096,1024]^T -
// 256x256 tile, BK=64, 8 waves (2Mx4N), 8-phase, vmcnt(6), LDS swizzle, T1/T5.
// LDS buf c: A_k0 @0, A_k1 @8192, B_k0 @16384, B_k1 @24576 (ushort offsets).
#define STAGE_HALF(GB, LOFF)                                                   \
  { _Pragma("unroll")                                                          \
    for (int i_ = 0; i_ < 2; ++i_){                                            \
      int c_ = tid + i_*512;                                                   \
      int row_ = c_ >> 2;                                                      \
      int ss_ = (c_ & 3) ^ ((row_ >> 2) & 3);                                  \
      const ushort* g_ = (GB) + (size_t)row_ * 1024 + ss_ * 8;                 \
      __builtin_amdgcn_global_load_lds(                                        \
        (const __attribute__((address_space(1))) void*)g_,                     \
        (__attribute__((address_space(3))) void*)&lds[(LOFF) + c_*8],          \
        16, 0, 0);                                                             \
    } }

#define LDA_FRAGS(KH)                                                          \
  { _Pragma("unroll")                                                          \
    for (int mi_ = 0; mi_ < 8; ++mi_){                                         \
      int r_ = wm*128 + mi_*16 + rsel;                                         \
      int uo_ = r_*32 + kq*8;                                                  \
      uo_ ^= ((uo_ >> 7) & 3) << 3;                                            \
      af[mi_] = *(const bf16x8*)&lds[cbase + (KH)*8192 + uo_];                 \
    } }

#define LDB_FRAGS(KH, NH)                                                      \
  { _Pragma("unroll")                                                          \
    for (int ni_ = 0; ni_ < 2; ++ni_){                                         \
      int r_ = wn*64 + (NH)*32 + ni_*16 + rsel;                                \
      int uo_ = r_*32 + kq*8;                                                  \
      uo_ ^= ((uo_ >> 7) & 3) << 3;                                            \
      bfr[ni_] = *(const bf16x8*)&lds[cbase + 16384 + (KH)*8192 + uo_];        \
    } }

#define MFMA_PH(NH)                                                            \
  { __builtin_amdgcn_s_setprio(1);                                             \
    _Pragma("unroll")                                                          \
    for (int mi_ = 0; mi_ < 8; ++mi_)                                          \
      { _Pragma("unroll")                                                      \
        for (int ni_ = 0; ni_ < 2; ++ni_)                                      \
          acc[mi_][(NH)*2+ni_] = __builtin_amdgcn_mfma_f32_16x16x32_bf16(      \
              af[mi_], bfr[ni_], acc[mi_][(NH)*2+ni_], 0, 0, 0); }             \
    __builtin_amdgcn_s_setprio(0); }

#define BAR() __builtin_amdgcn_s_barrier()

__global__ __launch_bounds__(512, 2) void gemm_big(const ushort* __restrict__ A,
                                                   const ushort* __restrict__ B,
                                                   ushort* __restrict__ C){
  __shared__ ushort lds[65536];       // 128 KB
  const int tid  = threadIdx.x;
  const int lane = tid & 63;
  const int w    = tid >> 6;          // 0..7
  const int wm   = w >> 2;            // 2 M-waves
  const int wn   = w & 3;             // 4 N-waves
  const int rsel = lane & 15;
  const int kq   = lane >> 4;

  // T1: bijective XCD swizzle (nwg=512, 512%8==0), column-major tile map
  int bid = blockIdx.x;
  int swz = (bid & 7) * 64 + (bid >> 3);
  const int rowBase = (swz & 31) * 256;   // 32 M-tiles
  const int colBase = (swz >> 5) * 256;   // 16 N-tiles

  const ushort* Ag = A + (size_t)rowBase * 1024;
  const ushort* Bg = B + (size_t)colBase * 1024;

  f32x4 acc[8][4] = {};
  bf16x8 af[8], bfr[2];

  // prologue: tile0 {A_k0,B_k0,A_k1,B_k1} -> buf0; tile1 {A_k0,B_k0,A_k1} -> buf1
  STAGE_HALF(Ag +  0, 0);
  STAGE_HALF(Bg +  0, 16384);
  STAGE_HALF(Ag + 32, 8192);
  STAGE_HALF(Bg + 32, 24576);
  STAGE_HALF(Ag + 64, 32768 + 0);
  STAGE_HALF(Bg + 64, 32768 + 16384);
  STAGE_HALF(Ag + 96, 32768 + 8192);
  asm volatile("s_waitcnt vmcnt(6)" ::: "memory");   // tile0 fully landed
  BAR();

  for (int t = 0; t < 16; ++t){
    const int cbase = (t & 1) * 32768;
    const int obase = cbase ^ 32768;
    // P1: compute (k0, n-quad0); issue B_k1(t+1) -> other buf
    LDA_FRAGS(0); LDB_FRAGS(0, 0);
    if (t + 1 < 16) STAGE_HALF(Bg + (t+1)*64 + 32, obase + 24576);
    BAR();
    MFMA_PH(0);
    BAR();
    // P2: compute (k0, n-quad1); issue A_k0(t+2) -> this buf (read done in P1)
    LDB_FRAGS(0, 1);
    if (t + 2 < 16) STAGE_HALF(Ag + (t+2)*64, cbase + 0);
    BAR();
    MFMA_PH(1);
    BAR();
    // P3: compute (k1, n-quad0); issue B_k0(t+2) (read done in P1/P2)
    LDA_FRAGS(1); LDB_FRAGS(1, 0);
    if (t + 2 < 16) STAGE_HALF(Bg + (t+2)*64, cbase + 16384);
    BAR();
    MFMA_PH(0);
    BAR();
    // P4: compute (k1, n-quad1); issue A_k1(t+2) (read done in P3)
    LDB_FRAGS(1, 1);
    if (t + 2 < 16) STAGE_HALF(Ag + (t+2)*64 + 32, cbase + 8192);
    BAR();
    MFMA_PH(1);
    // counted vmcnt: 3 half-tiles (6 loads) allowed in flight; tail drains
    if (t + 2 < 16) { asm volatile("s_waitcnt vmcnt(6)" ::: "memory"); }
    else            { asm volatile("s_waitcnt vmcnt(0)" ::: "memory"); }
    BAR();
  }

  #pragma unroll
  for (int mi = 0; mi < 8; ++mi){
    int r0 = rowBase + wm*128 + mi*16 + (lane >> 4) * 4;
    #pragma unroll
    for (int j = 0; j < 4; ++j){
      int c0 = colBase + wn*64 + j*16 + rsel;
      #pragma unroll
      for (int q = 0; q < 4; ++q)
        C[(size_t)(r0 + q) * Ee + c0] = f2bf(acc[mi][j][q]);
    }
  }
}

// ---------------- wave-per-output dot kernels (fp32) ------------------------
__global__ __launch_bounds__(256) void k_z0(const float* __restrict__ Wout,
                                            const float* __restrict__ s0,
                                            float* __restrict__ z0){
  int gid  = blockIdx.x * 4 + (threadIdx.x >> 6);
  int lane = threadIdx.x & 63;
  int d = gid & 1023, k = (gid >> 10) & 3, b = gid >> 12;
  const float* wrow = Wout + (size_t)d * Ee + k * Dd;
  const float* sv   = s0 + ((size_t)(b*Kk + k) << 10);
  float s = 0.f;
  #pragma unroll
  for (int j = 0; j < 16; ++j) s += wrow[lane + j*64] * sv[lane + j*64];
  for (int off = 32; off; off >>= 1) s += __shfl_down(s, off);
  if (lane == 0) z0[gid] = s;
}

__global__ __launch_bounds__(256) void k_cterm(const float* __restrict__ Wout,
                                               const float* __restrict__ b_in,
                                               float* __restrict__ cterm){
  int gid  = blockIdx.x * 4 + (threadIdx.x >> 6);
  int lane = threadIdx.x & 63;
  int d = gid & 1023, k = gid >> 10;
  const float* wrow = Wout + (size_t)d * Ee + k * Dd;
  const float* bv   = b_in + k * Dd;
  float s = 0.f;
  #pragma unroll
  for (int j = 0; j < 16; ++j) s += wrow[lane + j*64] * bv[lane + j*64];
  for (int off = 32; off; off >>= 1) s += __shfl_down(s, off);
  if (lane == 0) cterm[gid] = s;
}

// ---------------- scan pass A: per-chunk carries ----------------------------
__global__ __launch_bounds__(256) void k_scanA(const ushort* __restrict__ Y,
                                               const float* __restrict__ dlog,
                                               float* __restrict__ carry){
  int x = blockIdx.x;
  int d = blockIdx.y * 256 + threadIdx.x;
  int c = x & 31, k = (x >> 5) & 3, b = x >> 7;
  float p = sigm(dlog[k]);
  float acc = 0.f;
  size_t base = ((size_t)(b*Tt + c*LCH)) * Ee + k * Dd + d;
  for (int i = 0; i < LCH; ++i){ acc = p * acc + bf2f(Y[base]); base += Ee; }
  carry[(size_t)x * Dd + d] = acc;
}

__global__ __launch_bounds__(256) void k_scanInc(const float* __restrict__ carry,
                                                 const float* __restrict__ z0,
                                                 const float* __restrict__ dlog,
                                                 float* __restrict__ incoming){
  int idx = blockIdx.x * 256 + threadIdx.x;
  int k = (idx >> 10) & 3;
  int bk = idx >> 10, d = idx & 1023;
  float p  = sigm(dlog[k]);
  float dL = powf(p, (float)LCH);
  float inc = z0[idx];
  for (int c = 0; c < NCH; ++c){
    size_t o = ((size_t)(bk * NCH + c)) * Dd + d;
    incoming[o] = inc;
    inc = dL * inc + carry[o];
  }
}

__global__ __launch_bounds__(256) void k_scanB(const ushort* __restrict__ Y,
                                               const float* __restrict__ incoming,
                                               const float* __restrict__ dlog,
                                               const float* __restrict__ b_out,
                                               const float* __restrict__ cterm,
                                               float* __restrict__ g){
  int x = blockIdx.x;
  int d = blockIdx.y * 256 + threadIdx.x;
  int c = x & 31, b = x >> 5;
  float p[4], z[4], ct[4], pw[4];
  #pragma unroll
  for (int k = 0; k < 4; ++k){
    p[k]  = sigm(dlog[k]);
    z[k]  = incoming[((size_t)(((b*Kk + k))*NCH + c)) * Dd + d];
    float omp = fmaxf(1.0f - p[k], 1e-30f);
    ct[k] = cterm[k * Dd + d] / omp;
    pw[k] = powf(p[k], (float)(c * LCH + 1));
  }
  float bo = b_out[d];
  size_t ybase = ((size_t)(b*Tt + c*LCH)) * Ee + d;
  size_t gbase = ((size_t)(b*Tt + c*LCH)) * Dd + d;
  for (int i = 0; i < LCH; ++i){
    float acc = bo;
    #pragma unroll
    for (int k = 0; k < 4; ++k){
      z[k] = p[k] * z[k] + bf2f(Y[ybase + (size_t)k * Dd]);
      acc += z[k] + ct[k] * (1.0f - pw[k]);
      pw[k] *= p[k];
    }
    g[gbase] = acc;
    ybase += Ee; gbase += Dd;
  }
}

// ---------------- v path (+ fused u -> bf16 conversion) ---------------------
__global__ __launch_bounds__(256) void k_prep(const float* __restrict__ u,
                                              const float* __restrict__ dlog,
                                              float* __restrict__ vpart,
                                              ushort* __restrict__ U_bf){
  int x = blockIdx.x;                    // b*NCH + c
  int d = blockIdx.y * 256 + threadIdx.x;
  int c = x & 31, b = x >> 5;
  float p[4], a[4] = {0.f, 0.f, 0.f, 0.f};
  #pragma unroll
  for (int k = 0; k < 4; ++k) p[k] = sigm(dlog[k]);
  size_t ub = ((size_t)(b*Tt + c*LCH)) * Dd + d;
  for (int i = 0; i < LCH; ++i){
    float uv = u[ub];
    U_bf[ub] = f2bf(uv);
    #pragma unroll
    for (int k = 0; k < 4; ++k) a[k] = p[k] * a[k] + uv;
    ub += Dd;
  }
  #pragma unroll
  for (int k = 0; k < 4; ++k)
    vpart[(((size_t)x) * Kk + k) * Dd + d] = a[k];
}

__global__ __launch_bounds__(256) void k_vcomb(const float* __restrict__ vpart,
                                               const float* __restrict__ dlog,
                                               float* __restrict__ vfull){
  int idx = blockIdx.x * 256 + threadIdx.x;
  int k = (idx >> 10) & 3, b = idx >> 12, d = idx & 1023;
  float p  = sigm(dlog[k]);
  float dL = powf(p, (float)LCH);
  float v = 0.f;
  for (int c = 0; c < NCH; ++c)
    v = dL * v + vpart[(((size_t)(b*NCH + c)) * Kk + k) * Dd + d];
  vfull[idx] = v;
}

__global__ __launch_bounds__(256) void k_slast(const float* __restrict__ W_in,
                                               const float* __restrict__ vfull,
                                               const float* __restrict__ s0,
                                               const float* __restrict__ b_in,
                                               const float* __restrict__ dlog,
                                               float* __restrict__ out){
  int gid  = blockIdx.x * 4 + (threadIdx.x >> 6);
  int lane = threadIdx.x & 63;
  int d = gid & 1023, k = (gid >> 10) & 3, b = gid >> 12;
  const float* wrow = W_in + (size_t)(k*Dd + d) * Dd;
  const float* vv   = vfull + ((size_t)(b*Kk + k) << 10);
  float s = 0.f;
  #pragma unroll
  for (int j = 0; j < 16; ++j) s += wrow[lane + j*64] * vv[lane + j*64];
  for (int off = 32; off; off >>= 1) s += __shfl_down(s, off);
  if (lane == 0){
    float p  = sigm(dlog[k]);
    float pT = powf(p, (float)Tt);
    float omp = 1.0f - p;
    float geo = (omp < 1e-12f) ? (float)Tt : (1.0f - pT) / omp;
    out[gid] = pT * s0[gid] + s + b_in[k*Dd + d] * geo;
  }
}

// ---------------------------------------------------------------------------
extern "C" void kernel_launch(void* const* d_in, const int* in_sizes, int n_in,
                              void* d_out, int out_size, void* d_ws, size_t ws_size,
                              hipStream_t stream){
  const float* u     = (const float*)d_in[0];
  const float* s0    = (const float*)d_in[1];
  const float* W_in  = (const float*)d_in[2];
  const float* b_in  = (const float*)d_in[3];
  const float* W_out = (const float*)d_in[4];
  const float* b_out = (const float*)d_in[5];
  const float* dlog  = (const float*)d_in[6];

  float* g_out     = (float*)d_out;                      // B*T*D
  float* slast_out = g_out + (size_t)BT * Dd;            // B*K*D

  char* ws = (char*)d_ws;
  if (ws_size < 115490816ull) return;
  ushort* U_bf    = (ushort*)(ws);                       // 16 MB
  ushort* WinT    = (ushort*)(ws + 16777216);            //  8 MB
  ushort* Wout_bf = (ushort*)(ws + 25165824);            //  8 MB
  ushort* Mcat    = (ushort*)(ws + 33554432);            //  8 MB
  ushort* Y       = (ushort*)(ws + 41943040);            // 64 MB
  float*  carry   = (float*)(ws + 109051904);            //  2 MB
  float*  incoming= (float*)(ws + 111149056);            //  2 MB
  float*  z0buf   = (float*)(ws + 113246208);            // 64 KB
  float*  cterm   = (float*)(ws + 113311744);            // 16 KB
  float*  vpart   = (float*)(ws + 113328128);            //  2 MB
  float*  vfull   = (float*)(ws + 115425280);            // 64 KB

  // prep: u -> U_bf (fused) + vpart; weight converts
  k_prep<<<dim3(128, 4), 256, 0, stream>>>(u, dlog, vpart, U_bf);
  k_f2bf4<<<4096, 256, 0, stream>>>((const float4*)W_out, (ushort4*)Wout_bf, Dd*Ee/4);
  k_transpose<<<dim3(32, 128), dim3(32, 8), 0, stream>>>(W_in, WinT);

  // Mcat[(k,d), d'] = sum_j Wout[d, kD+j] * WinT[d', kD+j]
  gemm_nt<<<dim3(8, 8, 4), 256, 0, stream>>>(Wout_bf, WinT, Mcat,
                                             1024, Ee, Ee, Dd,
                                             1024L, 1024L, 1048576L);
  // Y[bt, (k,d)] = sum_d' U[bt, d'] * Mcat[(k,d), d']  -- 8-phase 256^2
  gemm_big<<<512, 512, 0, stream>>>(U_bf, Mcat, Y);

  // scan-init terms
  k_z0<<<4096, 256, 0, stream>>>(W_out, s0, z0buf);
  k_cterm<<<1024, 256, 0, stream>>>(W_out, b_in, cterm);

  // chunked scan over t
  k_scanA<<<dim3(512, 4), 256, 0, stream>>>(Y, dlog, carry);
  k_scanInc<<<64, 256, 0, stream>>>(carry, z0buf, dlog, incoming);
  k_scanB<<<dim3(128, 4), 256, 0, stream>>>(Y, incoming, dlog, b_out, cterm, g_out);

  // s_last path
  k_vcomb<<<64, 256, 0, stream>>>(vpart, dlog, vfull);
  k_slast<<<4096, 256, 0, stream>>>(W_in, vfull, s0, b_in, dlog, slast_out);
}

// Round 5
// 170.880 us; speedup vs baseline: 1.1891x; 1.0686x over previous
//
#include <hip/hip_runtime.h>

// ---------------------------------------------------------------------------
// StateBank: g = W_out @ scan(W_in @ u), restructured as
//   M_k = W_out_k @ W_in_k  (composite, k=0..3, each 1024x1024)
//   Y[b,t,(k,d)] = sum_d' M_k[d,d'] u[b,t,d']       (one 8192x4096x1024 GEMM)
//   z_k[b,t,d] = decay_k z_k[b,t-1,d] + Y[..]       (chunked parallel scan)
//   g[b,t,d] = b_out[d] + sum_k z_k + closed-form b_in/s0 terms
//   s_last[b,k,d] = decay^T s0 + W_in_k @ v_k[b] + b_in geom term
// Big GEMM: 256x256 tile, BK=64, 8 waves, 8-phase, counted vmcnt(6), LDS
// swizzle, setprio. XCD map: 8Mx8N region per XCD (fetch 8x(4+4)MB=64MB vs
// column walk's 136MB). Epilogue: acc -> LDS (32B-XOR swizzle) -> coalesced
// 16B Y writes + fused per-chunk scan carries (scanA kernel eliminated).
// ---------------------------------------------------------------------------

#define Bb 4
#define Tt 2048
#define Dd 1024
#define Kk 4
#define BT (Bb*Tt)          // 8192
#define Ee (Kk*Dd)          // 4096
#define NCH 32              // scan chunks
#define LCH 64              // chunk length (NCH*LCH = T)

typedef __bf16 bf16x8 __attribute__((ext_vector_type(8)));
typedef float  f32x4  __attribute__((ext_vector_type(4)));

__device__ __forceinline__ float bf2f(ushort u){
  union { unsigned int i; float f; } x; x.i = ((unsigned int)u) << 16; return x.f;
}
__device__ __forceinline__ ushort f2bf(float f){
  union { unsigned int i; float f; } x; x.f = f;
  unsigned int i = x.i;
  return (ushort)((i + 0x7FFFu + ((i >> 16) & 1u)) >> 16);   // RNE
}
__device__ __forceinline__ float sigm(float x){ return 1.0f / (1.0f + expf(-x)); }

// ---------------- convert f32 -> bf16 (vectorized) ----------------
__global__ __launch_bounds__(256) void k_f2bf4(const float4* __restrict__ in,
                                               ushort4* __restrict__ out, int n4){
  int i = blockIdx.x * 256 + threadIdx.x;
  if (i < n4){
    float4 v = in[i];
    ushort4 o; o.x = f2bf(v.x); o.y = f2bf(v.y); o.z = f2bf(v.z); o.w = f2bf(v.w);
    out[i] = o;
  }
}

// ---------------- transpose W_in (4096x1024 f32) -> WinT (1024x4096 bf16) ---
__global__ __launch_bounds__(256) void k_transpose(const float* __restrict__ in,
                                                   ushort* __restrict__ out){
  __shared__ float tile[32][33];
  int tx = threadIdx.x, ty = threadIdx.y;          // 32 x 8
  int c0 = blockIdx.x * 32, r0 = blockIdx.y * 32;  // cols of in, rows of in
  #pragma unroll
  for (int j = 0; j < 4; ++j)
    tile[ty + j*8][tx] = in[(size_t)(r0 + ty + j*8) * Dd + c0 + tx];
  __syncthreads();
  #pragma unroll
  for (int j = 0; j < 4; ++j)
    out[(size_t)(c0 + ty + j*8) * Ee + r0 + tx] = f2bf(tile[tx][ty + j*8]);
}

// ---------------- small NT GEMM (m97 structure) for Mcat --------------------
__global__ __launch_bounds__(256) void gemm_nt(const ushort* __restrict__ A,
                                               const ushort* __restrict__ B,
                                               ushort* __restrict__ C,
                                               int Kred, int lda, int ldb, int ldc,
                                               long aBatch, long bBatch, long cBatch){
  __shared__ ushort As[128 * 32];
  __shared__ ushort Bs[128 * 32];
  A += (long)blockIdx.z * aBatch;
  B += (long)blockIdx.z * bBatch;
  C += (long)blockIdx.z * cBatch;
  const int tid  = threadIdx.x;
  const int lane = tid & 63;
  const int w    = tid >> 6;
  const int wr   = w >> 1, wc = w & 1;
  const int rowBase = blockIdx.x * 128;
  const int colBase = blockIdx.y * 128;

  f32x4 acc[4][4] = {};
  const int krow = (lane >> 4) * 8;
  const int rsel = lane & 15;

  for (int kk = 0; kk < Kred; kk += 32){
    __syncthreads();
    #pragma unroll
    for (int i = 0; i < 2; ++i){
      int c  = i * 256 + tid;
      int r  = c >> 2;
      int c8 = (c & 3) * 8;
      const ushort* ga = A + (size_t)(rowBase + r) * lda + kk + c8;
      const ushort* gb = B + (size_t)(colBase + r) * ldb + kk + c8;
      __builtin_amdgcn_global_load_lds((const __attribute__((address_space(1))) void*)ga,
                                       (__attribute__((address_space(3))) void*)&As[c * 8],
                                       16, 0, 0);
      __builtin_amdgcn_global_load_lds((const __attribute__((address_space(1))) void*)gb,
                                       (__attribute__((address_space(3))) void*)&Bs[c * 8],
                                       16, 0, 0);
    }
    asm volatile("s_waitcnt vmcnt(0)" ::: "memory");
    __syncthreads();

    bf16x8 Af[4], Bf[4];
    #pragma unroll
    for (int mi = 0; mi < 4; ++mi)
      Af[mi] = *(const bf16x8*)&As[(wr*64 + mi*16 + rsel) * 32 + krow];
    #pragma unroll
    for (int ni = 0; ni < 4; ++ni)
      Bf[ni] = *(const bf16x8*)&Bs[(wc*64 + ni*16 + rsel) * 32 + krow];
    #pragma unroll
    for (int mi = 0; mi < 4; ++mi)
      #pragma unroll
      for (int ni = 0; ni < 4; ++ni)
        acc[mi][ni] = __builtin_amdgcn_mfma_f32_16x16x32_bf16(Af[mi], Bf[ni], acc[mi][ni], 0, 0, 0);
  }

  #pragma unroll
  for (int mi = 0; mi < 4; ++mi){
    #pragma unroll
    for (int ni = 0; ni < 4; ++ni){
      int r0 = rowBase + wr*64 + mi*16 + (lane >> 4) * 4;
      int c0 = colBase + wc*64 + ni*16 + (lane & 15);
      #pragma unroll
      for (int q = 0; q < 4; ++q)
        C[(size_t)(r0 + q) * ldc + c0] = f2bf(acc[mi][ni][q]);
    }
  }
}

// ---------------- big GEMM: Y[8192,4096] = U[8192,1024] @ Mcat[4096,1024]^T -
// LDS buf c: A_k0 @0, A_k1 @8192, B_k0 @16384, B_k1 @24576 (ushort offsets).
#define STAGE_HALF(GB, LOFF)                                                   \
  { _Pragma("unroll")                                                          \
    for (int i_ = 0; i_ < 2; ++i_){                                            \
      int c_ = tid + i_*512;                                                   \
      int row_ = c_ >> 2;                                                      \
      int ss_ = (c_ & 3) ^ ((row_ >> 2) & 3);                                  \
      const ushort* g_ = (GB) + (size_t)row_ * 1024 + ss_ * 8;                 \
      __builtin_amdgcn_global_load_lds(                                        \
        (const __attribute__((address_space(1))) void*)g_,                     \
        (__attribute__((address_space(3))) void*)&lds[(LOFF) + c_*8],          \
        16, 0, 0);                                                             \
    } }

#define LDA_FRAGS(KH)                                                          \
  { _Pragma("unroll")                                                          \
    for (int mi_ = 0; mi_ < 8; ++mi_){                                         \
      int r_ = wm*128 + mi_*16 + rsel;                                         \
      int uo_ = r_*32 + kq*8;                                                  \
      uo_ ^= ((uo_ >> 7) & 3) << 3;                                            \
      af[mi_] = *(const bf16x8*)&lds[cbase + (KH)*8192 + uo_];                 \
    } }

#define LDB_FRAGS(KH, NH)                                                      \
  { _Pragma("unroll")                                                          \
    for (int ni_ = 0; ni_ < 2; ++ni_){                                         \
      int r_ = wn*64 + (NH)*32 + ni_*16 + rsel;                                \
      int uo_ = r_*32 + kq*8;                                                  \
      uo_ ^= ((uo_ >> 7) & 3) << 3;                                            \
      bfr[ni_] = *(const bf16x8*)&lds[cbase + 16384 + (KH)*8192 + uo_];        \
    } }

#define MFMA_PH(NH)                                                            \
  { __builtin_amdgcn_s_setprio(1);                                             \
    _Pragma("unroll")                                                          \
    for (int mi_ = 0; mi_ < 8; ++mi_)                                          \
      { _Pragma("unroll")                                                      \
        for (int ni_ = 0; ni_ < 2; ++ni_)                                      \
          acc[mi_][(NH)*2+ni_] = __builtin_amdgcn_mfma_f32_16x16x32_bf16(      \
              af[mi_], bfr[ni_], acc[mi_][(NH)*2+ni_], 0, 0, 0); }             \
    __builtin_amdgcn_s_setprio(0); }

#define BAR() __builtin_amdgcn_s_barrier()

__global__ __launch_bounds__(512, 2) void gemm_big(const ushort* __restrict__ A,
                                                   const ushort* __restrict__ B,
                                                   ushort* __restrict__ C,
                                                   const float* __restrict__ dlog,
                                                   float* __restrict__ carry){
  __shared__ ushort lds[65536];       // 128 KB
  const int tid  = threadIdx.x;
  const int lane = tid & 63;
  const int w    = tid >> 6;          // 0..7
  const int wm   = w >> 2;            // 2 M-waves
  const int wn   = w & 3;             // 4 N-waves
  const int rsel = lane & 15;
  const int kq   = lane >> 4;

  // XCD map: round-robin dispatch (xcd = bid&7); each XCD owns an 8Mx8N
  // tile region -> per-XCD operand footprint 4MB A + 4MB B (vs 16MB column
  // walk). Resident 32 blocks walk 8Mx4N (6MB ~ L2).
  int bid = blockIdx.x;
  int xcd = bid & 7, rr = bid >> 3;   // rr in 0..63
  const int rowBase = (((xcd >> 1) << 3) + (rr & 7)) * 256;   // 32 M-tiles
  const int colBase = (((xcd & 1) << 3) + (rr >> 3)) * 256;   // 16 N-tiles

  const ushort* Ag = A + (size_t)rowBase * 1024;
  const ushort* Bg = B + (size_t)colBase * 1024;

  f32x4 acc[8][4] = {};
  bf16x8 af[8], bfr[2];

  // prologue: tile0 {A_k0,B_k0,A_k1,B_k1} -> buf0; tile1 {A_k0,B_k0,A_k1} -> buf1
  STAGE_HALF(Ag +  0, 0);
  STAGE_HALF(Bg +  0, 16384);
  STAGE_HALF(Ag + 32, 8192);
  STAGE_HALF(Bg + 32, 24576);
  STAGE_HALF(Ag + 64, 32768 + 0);
  STAGE_HALF(Bg + 64, 32768 + 16384);
  STAGE_HALF(Ag + 96, 32768 + 8192);
  asm volatile("s_waitcnt vmcnt(6)" ::: "memory");   // tile0 fully landed
  BAR();

  for (int t = 0; t < 16; ++t){
    const int cbase = (t & 1) * 32768;
    const int obase = cbase ^ 32768;
    // P1: compute (k0, n-quad0); issue B_k1(t+1) -> other buf
    LDA_FRAGS(0); LDB_FRAGS(0, 0);
    if (t + 1 < 16) STAGE_HALF(Bg + (t+1)*64 + 32, obase + 24576);
    BAR();
    MFMA_PH(0);
    BAR();
    // P2: compute (k0, n-quad1); issue A_k0(t+2) -> this buf (read done in P1)
    LDB_FRAGS(0, 1);
    if (t + 2 < 16) STAGE_HALF(Ag + (t+2)*64, cbase + 0);
    BAR();
    MFMA_PH(1);
    BAR();
    // P3: compute (k1, n-quad0); issue B_k0(t+2) (read done in P1/P2)
    LDA_FRAGS(1); LDB_FRAGS(1, 0);
    if (t + 2 < 16) STAGE_HALF(Bg + (t+2)*64, cbase + 16384);
    BAR();
    MFMA_PH(0);
    BAR();
    // P4: compute (k1, n-quad1); issue A_k1(t+2) (read done in P3)
    LDB_FRAGS(1, 1);
    if (t + 2 < 16) STAGE_HALF(Ag + (t+2)*64 + 32, cbase + 8192);
    BAR();
    MFMA_PH(1);
    // counted vmcnt: 3 half-tiles (6 loads) allowed in flight; tail drains
    if (t + 2 < 16) { asm volatile("s_waitcnt vmcnt(6)" ::: "memory"); }
    else            { asm volatile("s_waitcnt vmcnt(0)" ::: "memory"); }
    BAR();
  }

  // ---- epilogue: stage C tile (256x256 bf16 = 128KB) into LDS with a 32B-
  // granular XOR swizzle (bank-conflict-free writes/reads), then (a) fused
  // per-64-row scan carries, (b) coalesced 16B/lane Y stores.
  #pragma unroll
  for (int mi = 0; mi < 8; ++mi){
    #pragma unroll
    for (int j = 0; j < 4; ++j){
      #pragma unroll
      for (int q = 0; q < 4; ++q){
        int row = wm*128 + mi*16 + (lane >> 4)*4 + q;
        int col = wn*64 + j*16 + rsel;
        int byte = row*512 + col*2;
        byte ^= ((row >> 2) & 3) << 5;
        *(ushort*)((char*)lds + byte) = f2bf(acc[mi][j][q]);
      }
    }
  }
  __syncthreads();

  // fused scanA: carry[(b*K+k)*NCH + ch][d] over this tile's 4 chunks of 64 t
  {
    const int k_blk = colBase >> 10;
    const int b_blk = rowBase >> 11;
    const int ch0   = (rowBase & 2047) >> 6;
    const int d0    = colBase & 1023;
    const float p   = sigm(dlog[k_blk]);
    #pragma unroll
    for (int s = 0; s < 2; ++s){
      int task = tid + s*512;
      int col = task & 255, ch = task >> 8;     // 256 cols x 4 chunks
      float a = 0.f;
      for (int i = 0; i < 64; ++i){
        int row = ch*64 + i;
        int byte = row*512 + col*2;
        byte ^= ((row >> 2) & 3) << 5;
        a = p * a + bf2f(*(const ushort*)((char*)lds + byte));
      }
      carry[(size_t)((b_blk*Kk + k_blk)*NCH + ch0 + ch) * Dd + d0 + col] = a;
    }
  }

  // coalesced Y write: 16B per lane, rows of 512B fully covered per wave-pair
  #pragma unroll
  for (int j = 0; j < 16; ++j){
    int idx = tid + j*512;            // 0..8191
    int r = idx >> 5, c8 = idx & 31;
    int byte = r*512 + c8*16;
    byte ^= ((r >> 2) & 3) << 5;
    f32x4 v = *(const f32x4*)((char*)lds + byte);
    *(f32x4*)&C[(size_t)(rowBase + r) * Ee + colBase + c8*8] = v;
  }
}

// ---------------- wave-per-output dot kernels (fp32) ------------------------
__global__ __launch_bounds__(256) void k_z0(const float* __restrict__ Wout,
                                            const float* __restrict__ s0,
                                            float* __restrict__ z0){
  int gid  = blockIdx.x * 4 + (threadIdx.x >> 6);
  int lane = threadIdx.x & 63;
  int d = gid & 1023, k = (gid >> 10) & 3, b = gid >> 12;
  const float* wrow = Wout + (size_t)d * Ee + k * Dd;
  const float* sv   = s0 + ((size_t)(b*Kk + k) << 10);
  float s = 0.f;
  #pragma unroll
  for (int j = 0; j < 16; ++j) s += wrow[lane + j*64] * sv[lane + j*64];
  for (int off = 32; off; off >>= 1) s += __shfl_down(s, off);
  if (lane == 0) z0[gid] = s;
}

__global__ __launch_bounds__(256) void k_cterm(const float* __restrict__ Wout,
                                               const float* __restrict__ b_in,
                                               float* __restrict__ cterm){
  int gid  = blockIdx.x * 4 + (threadIdx.x >> 6);
  int lane = threadIdx.x & 63;
  int d = gid & 1023, k = gid >> 10;
  const float* wrow = Wout + (size_t)d * Ee + k * Dd;
  const float* bv   = b_in + k * Dd;
  float s = 0.f;
  #pragma unroll
  for (int j = 0; j < 16; ++j) s += wrow[lane + j*64] * bv[lane + j*64];
  for (int off = 32; off; off >>= 1) s += __shfl_down(s, off);
  if (lane == 0) cterm[gid] = s;
}

__global__ __launch_bounds__(256) void k_scanInc(const float* __restrict__ carry,
                                                 const float* __restrict__ z0,
                                                 const float* __restrict__ dlog,
                                                 float* __restrict__ incoming){
  int idx = blockIdx.x * 256 + threadIdx.x;
  int k = (idx >> 10) & 3;
  int bk = idx >> 10, d = idx & 1023;
  float p  = sigm(dlog[k]);
  float dL = powf(p, (float)LCH);
  float inc = z0[idx];
  for (int c = 0; c < NCH; ++c){
    size_t o = ((size_t)(bk * NCH + c)) * Dd + d;
    incoming[o] = inc;
    inc = dL * inc + carry[o];
  }
}

__global__ __launch_bounds__(256) void k_scanB(const ushort* __restrict__ Y,
                                               const float* __restrict__ incoming,
                                               const float* __restrict__ dlog,
                                               const float* __restrict__ b_out,
                                               const float* __restrict__ cterm,
                                               float* __restrict__ g){
  int x = blockIdx.x;
  int d = blockIdx.y * 256 + threadIdx.x;
  int c = x & 31, b = x >> 5;
  float p[4], z[4], ct[4], pw[4];
  #pragma unroll
  for (int k = 0; k < 4; ++k){
    p[k]  = sigm(dlog[k]);
    z[k]  = incoming[((size_t)(((b*Kk + k))*NCH + c)) * Dd + d];
    float omp = fmaxf(1.0f - p[k], 1e-30f);
    ct[k] = cterm[k * Dd + d] / omp;
    pw[k] = powf(p[k], (float)(c * LCH + 1));
  }
  float bo = b_out[d];
  size_t ybase = ((size_t)(b*Tt + c*LCH)) * Ee + d;
  size_t gbase = ((size_t)(b*Tt + c*LCH)) * Dd + d;
  for (int i = 0; i < LCH; ++i){
    float acc = bo;
    #pragma unroll
    for (int k = 0; k < 4; ++k){
      z[k] = p[k] * z[k] + bf2f(Y[ybase + (size_t)k * Dd]);
      acc += z[k] + ct[k] * (1.0f - pw[k]);
      pw[k] *= p[k];
    }
    g[gbase] = acc;
    ybase += Ee; gbase += Dd;
  }
}

// ---------------- v path (+ fused u -> bf16 conversion) ---------------------
__global__ __launch_bounds__(256) void k_prep(const float* __restrict__ u,
                                              const float* __restrict__ dlog,
                                              float* __restrict__ vpart,
                                              ushort* __restrict__ U_bf){
  int x = blockIdx.x;                    // b*NCH + c
  int d = blockIdx.y * 256 + threadIdx.x;
  int c = x & 31, b = x >> 5;
  float p[4], a[4] = {0.f, 0.f, 0.f, 0.f};
  #pragma unroll
  for (int k = 0; k < 4; ++k) p[k] = sigm(dlog[k]);
  size_t ub = ((size_t)(b*Tt + c*LCH)) * Dd + d;
  for (int i = 0; i < LCH; ++i){
    float uv = u[ub];
    U_bf[ub] = f2bf(uv);
    #pragma unroll
    for (int k = 0; k < 4; ++k) a[k] = p[k] * a[k] + uv;
    ub += Dd;
  }
  #pragma unroll
  for (int k = 0; k < 4; ++k)
    vpart[(((size_t)x) * Kk + k) * Dd + d] = a[k];
}

__global__ __launch_bounds__(256) void k_vcomb(const float* __restrict__ vpart,
                                               const float* __restrict__ dlog,
                                               float* __restrict__ vfull){
  int idx = blockIdx.x * 256 + threadIdx.x;
  int k = (idx >> 10) & 3, b = idx >> 12, d = idx & 1023;
  float p  = sigm(dlog[k]);
  float dL = powf(p, (float)LCH);
  float v = 0.f;
  for (int c = 0; c < NCH; ++c)
    v = dL * v + vpart[(((size_t)(b*NCH + c)) * Kk + k) * Dd + d];
  vfull[idx] = v;
}

__global__ __launch_bounds__(256) void k_slast(const float* __restrict__ W_in,
                                               const float* __restrict__ vfull,
                                               const float* __restrict__ s0,
                                               const float* __restrict__ b_in,
                                               const float* __restrict__ dlog,
                                               float* __restrict__ out){
  int gid  = blockIdx.x * 4 + (threadIdx.x >> 6);
  int lane = threadIdx.x & 63;
  int d = gid & 1023, k = (gid >> 10) & 3, b = gid >> 12;
  const float* wrow = W_in + (size_t)(k*Dd + d) * Dd;
  const float* vv   = vfull + ((size_t)(b*Kk + k) << 10);
  float s = 0.f;
  #pragma unroll
  for (int j = 0; j < 16; ++j) s += wrow[lane + j*64] * vv[lane + j*64];
  for (int off = 32; off; off >>= 1) s += __shfl_down(s, off);
  if (lane == 0){
    float p  = sigm(dlog[k]);
    float pT = powf(p, (float)Tt);
    float omp = 1.0f - p;
    float geo = (omp < 1e-12f) ? (float)Tt : (1.0f - pT) / omp;
    out[gid] = pT * s0[gid] + s + b_in[k*Dd + d] * geo;
  }
}

// ---------------------------------------------------------------------------
extern "C" void kernel_launch(void* const* d_in, const int* in_sizes, int n_in,
                              void* d_out, int out_size, void* d_ws, size_t ws_size,
                              hipStream_t stream){
  const float* u     = (const float*)d_in[0];
  const float* s0    = (const float*)d_in[1];
  const float* W_in  = (const float*)d_in[2];
  const float* b_in  = (const float*)d_in[3];
  const float* W_out = (const float*)d_in[4];
  const float* b_out = (const float*)d_in[5];
  const float* dlog  = (const float*)d_in[6];

  float* g_out     = (float*)d_out;                      // B*T*D
  float* slast_out = g_out + (size_t)BT * Dd;            // B*K*D

  char* ws = (char*)d_ws;
  if (ws_size < 115490816ull) return;
  ushort* U_bf    = (ushort*)(ws);                       // 16 MB
  ushort* WinT    = (ushort*)(ws + 16777216);            //  8 MB
  ushort* Wout_bf = (ushort*)(ws + 25165824);            //  8 MB
  ushort* Mcat    = (ushort*)(ws + 33554432);            //  8 MB
  ushort* Y       = (ushort*)(ws + 41943040);            // 64 MB
  float*  carry   = (float*)(ws + 109051904);            //  2 MB
  float*  incoming= (float*)(ws + 111149056);            //  2 MB
  float*  z0buf   = (float*)(ws + 113246208);            // 64 KB
  float*  cterm   = (float*)(ws + 113311744);            // 16 KB
  float*  vpart   = (float*)(ws + 113328128);            //  2 MB
  float*  vfull   = (float*)(ws + 115425280);            // 64 KB

  // prep: u -> U_bf (fused) + vpart; weight converts
  k_prep<<<dim3(128, 4), 256, 0, stream>>>(u, dlog, vpart, U_bf);
  k_f2bf4<<<4096, 256, 0, stream>>>((const float4*)W_out, (ushort4*)Wout_bf, Dd*Ee/4);
  k_transpose<<<dim3(32, 128), dim3(32, 8), 0, stream>>>(W_in, WinT);

  // Mcat[(k,d), d'] = sum_j Wout[d, kD+j] * WinT[d', kD+j]
  gemm_nt<<<dim3(8, 8, 4), 256, 0, stream>>>(Wout_bf, WinT, Mcat,
                                             1024, Ee, Ee, Dd,
                                             1024L, 1024L, 1048576L);
  // Y = U @ Mcat^T, 8-phase 256^2, fused chunk-carry epilogue (was scanA)
  gemm_big<<<512, 512, 0, stream>>>(U_bf, Mcat, Y, dlog, carry);

  // scan-init terms
  k_z0<<<4096, 256, 0, stream>>>(W_out, s0, z0buf);
  k_cterm<<<1024, 256, 0, stream>>>(W_out, b_in, cterm);

  // cross-chunk scan + apply
  k_scanInc<<<64, 256, 0, stream>>>(carry, z0buf, dlog, incoming);
  k_scanB<<<dim3(128, 4), 256, 0, stream>>>(Y, incoming, dlog, b_out, cterm, g_out);

  // s_last path
  k_vcomb<<<64, 256, 0, stream>>>(vpart, dlog, vfull);
  k_slast<<<4096, 256, 0, stream>>>(W_in, vfull, s0, b_in, dlog, slast_out);
}

// Round 6
// 170.746 us; speedup vs baseline: 1.1900x; 1.0008x over previous
//
#include <hip/hip_runtime.h>

// ---------------------------------------------------------------------------
// StateBank: g = W_out @ scan(W_in @ u), restructured as
//   M_k = W_out_k @ W_in_k  (composite, k=0..3, each 1024x1024)
//   Y[b,t,(k,d)] = sum_d' M_k[d,d'] u[b,t,d']       (one 8192x4096x1024 GEMM)
//   z_k[b,t,d] = decay_k z_k[b,t-1,d] + Y[..]       (chunked parallel scan)
//   g[b,t,d] = b_out[d] + sum_k z_k + closed-form b_in/s0 terms
//   s_last[b,k,d] = decay^T s0 + W_in_k @ v_k[b] + b_in geom term
// Big GEMM: 256x256, BK=64, 8 waves. Phases = (k-half, m-half): balanced
// 8/4/8/4 ds_reads per phase, lgkmcnt(0)+sched_barrier AFTER the barrier
// (barrier absorbs LDS drain), 1 half-tile stage per phase, vmcnt(6) at
// P2/P4 ends (tail-tightened). Region XCD map. Fused carry epilogue.
// ---------------------------------------------------------------------------

#define Bb 4
#define Tt 2048
#define Dd 1024
#define Kk 4
#define BT (Bb*Tt)          // 8192
#define Ee (Kk*Dd)          // 4096
#define NCH 32              // scan chunks
#define LCH 64              // chunk length (NCH*LCH = T)

typedef __bf16 bf16x8 __attribute__((ext_vector_type(8)));
typedef float  f32x4  __attribute__((ext_vector_type(4)));

__device__ __forceinline__ float bf2f(ushort u){
  union { unsigned int i; float f; } x; x.i = ((unsigned int)u) << 16; return x.f;
}
__device__ __forceinline__ ushort f2bf(float f){
  union { unsigned int i; float f; } x; x.f = f;
  unsigned int i = x.i;
  return (ushort)((i + 0x7FFFu + ((i >> 16) & 1u)) >> 16);   // RNE
}
__device__ __forceinline__ float sigm(float x){ return 1.0f / (1.0f + expf(-x)); }

// ---------------- convert f32 -> bf16 (vectorized) ----------------
__global__ __launch_bounds__(256) void k_f2bf4(const float4* __restrict__ in,
                                               ushort4* __restrict__ out, int n4){
  int i = blockIdx.x * 256 + threadIdx.x;
  if (i < n4){
    float4 v = in[i];
    ushort4 o; o.x = f2bf(v.x); o.y = f2bf(v.y); o.z = f2bf(v.z); o.w = f2bf(v.w);
    out[i] = o;
  }
}

// ---------------- transpose W_in (4096x1024 f32) -> WinT (1024x4096 bf16) ---
__global__ __launch_bounds__(256) void k_transpose(const float* __restrict__ in,
                                                   ushort* __restrict__ out){
  __shared__ float tile[32][33];
  int tx = threadIdx.x, ty = threadIdx.y;          // 32 x 8
  int c0 = blockIdx.x * 32, r0 = blockIdx.y * 32;  // cols of in, rows of in
  #pragma unroll
  for (int j = 0; j < 4; ++j)
    tile[ty + j*8][tx] = in[(size_t)(r0 + ty + j*8) * Dd + c0 + tx];
  __syncthreads();
  #pragma unroll
  for (int j = 0; j < 4; ++j)
    out[(size_t)(c0 + ty + j*8) * Ee + r0 + tx] = f2bf(tile[tx][ty + j*8]);
}

// ---------------- small NT GEMM (m97 structure) for Mcat --------------------
__global__ __launch_bounds__(256) void gemm_nt(const ushort* __restrict__ A,
                                               const ushort* __restrict__ B,
                                               ushort* __restrict__ C,
                                               int Kred, int lda, int ldb, int ldc,
                                               long aBatch, long bBatch, long cBatch){
  __shared__ ushort As[128 * 32];
  __shared__ ushort Bs[128 * 32];
  A += (long)blockIdx.z * aBatch;
  B += (long)blockIdx.z * bBatch;
  C += (long)blockIdx.z * cBatch;
  const int tid  = threadIdx.x;
  const int lane = tid & 63;
  const int w    = tid >> 6;
  const int wr   = w >> 1, wc = w & 1;
  const int rowBase = blockIdx.x * 128;
  const int colBase = blockIdx.y * 128;

  f32x4 acc[4][4] = {};
  const int krow = (lane >> 4) * 8;
  const int rsel = lane & 15;

  for (int kk = 0; kk < Kred; kk += 32){
    __syncthreads();
    #pragma unroll
    for (int i = 0; i < 2; ++i){
      int c  = i * 256 + tid;
      int r  = c >> 2;
      int c8 = (c & 3) * 8;
      const ushort* ga = A + (size_t)(rowBase + r) * lda + kk + c8;
      const ushort* gb = B + (size_t)(colBase + r) * ldb + kk + c8;
      __builtin_amdgcn_global_load_lds((const __attribute__((address_space(1))) void*)ga,
                                       (__attribute__((address_space(3))) void*)&As[c * 8],
                                       16, 0, 0);
      __builtin_amdgcn_global_load_lds((const __attribute__((address_space(1))) void*)gb,
                                       (__attribute__((address_space(3))) void*)&Bs[c * 8],
                                       16, 0, 0);
    }
    asm volatile("s_waitcnt vmcnt(0)" ::: "memory");
    __syncthreads();

    bf16x8 Af[4], Bf[4];
    #pragma unroll
    for (int mi = 0; mi < 4; ++mi)
      Af[mi] = *(const bf16x8*)&As[(wr*64 + mi*16 + rsel) * 32 + krow];
    #pragma unroll
    for (int ni = 0; ni < 4; ++ni)
      Bf[ni] = *(const bf16x8*)&Bs[(wc*64 + ni*16 + rsel) * 32 + krow];
    #pragma unroll
    for (int mi = 0; mi < 4; ++mi)
      #pragma unroll
      for (int ni = 0; ni < 4; ++ni)
        acc[mi][ni] = __builtin_amdgcn_mfma_f32_16x16x32_bf16(Af[mi], Bf[ni], acc[mi][ni], 0, 0, 0);
  }

  #pragma unroll
  for (int mi = 0; mi < 4; ++mi){
    #pragma unroll
    for (int ni = 0; ni < 4; ++ni){
      int r0 = rowBase + wr*64 + mi*16 + (lane >> 4) * 4;
      int c0 = colBase + wc*64 + ni*16 + (lane & 15);
      #pragma unroll
      for (int q = 0; q < 4; ++q)
        C[(size_t)(r0 + q) * ldc + c0] = f2bf(acc[mi][ni][q]);
    }
  }
}

// ---------------- big GEMM: Y[8192,4096] = U[8192,1024] @ Mcat[4096,1024]^T -
// LDS buf: A_k0 @0, A_k1 @8192, B_k0 @16384, B_k1 @24576 (ushort offsets).
#define STAGE_HALF(GB, LOFF)                                                   \
  { _Pragma("unroll")                                                          \
    for (int i_ = 0; i_ < 2; ++i_){                                            \
      int c_ = tid + i_*512;                                                   \
      int row_ = c_ >> 2;                                                      \
      int ss_ = (c_ & 3) ^ ((row_ >> 2) & 3);                                  \
      const ushort* g_ = (GB) + (size_t)row_ * 1024 + ss_ * 8;                 \
      __builtin_amdgcn_global_load_lds(                                        \
        (const __attribute__((address_space(1))) void*)g_,                     \
        (__attribute__((address_space(3))) void*)&lds[(LOFF) + c_*8],          \
        16, 0, 0);                                                             \
    } }

#define LDA_H(KH, MH)                                                          \
  { _Pragma("unroll")                                                          \
    for (int mi_ = 0; mi_ < 4; ++mi_){                                         \
      int r_ = wm*128 + (MH)*64 + mi_*16 + rsel;                               \
      int uo_ = r_*32 + kq*8;                                                  \
      uo_ ^= ((uo_ >> 7) & 3) << 3;                                            \
      af[mi_] = *(const bf16x8*)&lds[cbase + (KH)*8192 + uo_];                 \
    } }

#define LDB_ALL(KH)                                                            \
  { _Pragma("unroll")                                                          \
    for (int ni_ = 0; ni_ < 4; ++ni_){                                         \
      int r_ = wn*64 + ni_*16 + rsel;                                          \
      int uo_ = r_*32 + kq*8;                                                  \
      uo_ ^= ((uo_ >> 7) & 3) << 3;                                            \
      bfr[ni_] = *(const bf16x8*)&lds[cbase + 16384 + (KH)*8192 + uo_];        \
    } }

#define WAIT_LGKM()                                                            \
  { asm volatile("s_waitcnt lgkmcnt(0)" ::: "memory");                         \
    __builtin_amdgcn_sched_barrier(0); }

#define MFMA_Q(MH)                                                             \
  { __builtin_amdgcn_s_setprio(1);                                             \
    _Pragma("unroll")                                                          \
    for (int mi_ = 0; mi_ < 4; ++mi_)                                          \
      { _Pragma("unroll")                                                      \
        for (int ni_ = 0; ni_ < 4; ++ni_)                                      \
          acc[(MH)*4+mi_][ni_] = __builtin_amdgcn_mfma_f32_16x16x32_bf16(      \
              af[mi_], bfr[ni_], acc[(MH)*4+mi_][ni_], 0, 0, 0); }             \
    __builtin_amdgcn_s_setprio(0); }

#define BAR() __builtin_amdgcn_s_barrier()

__global__ __launch_bounds__(512, 2) void gemm_big(const ushort* __restrict__ A,
                                                   const ushort* __restrict__ B,
                                                   ushort* __restrict__ C,
                                                   const float* __restrict__ dlog,
                                                   float* __restrict__ carry){
  __shared__ ushort lds[65536];       // 128 KB
  const int tid  = threadIdx.x;
  const int lane = tid & 63;
  const int w    = tid >> 6;          // 0..7
  const int wm   = w >> 2;            // 2 M-waves
  const int wn   = w & 3;             // 4 N-waves
  const int rsel = lane & 15;
  const int kq   = lane >> 4;

  // XCD region map: 8Mx8N tile region per XCD (per-XCD footprint 4+4 MB).
  int bid = blockIdx.x;
  int xcd = bid & 7, rr = bid >> 3;   // rr in 0..63
  const int rowBase = (((xcd >> 1) << 3) + (rr & 7)) * 256;   // 32 M-tiles
  const int colBase = (((xcd & 1) << 3) + (rr >> 3)) * 256;   // 16 N-tiles

  const ushort* Ag = A + (size_t)rowBase * 1024;
  const ushort* Bg = B + (size_t)colBase * 1024;

  f32x4 acc[8][4] = {};
  bf16x8 af[4], bfr[4];

  // prologue: tile0 all 4 halves + tile1 {A_k0, B_k0}; drain; barrier.
  STAGE_HALF(Ag +  0, 0);
  STAGE_HALF(Bg +  0, 16384);
  STAGE_HALF(Ag + 32, 8192);
  STAGE_HALF(Bg + 32, 24576);
  STAGE_HALF(Ag + 64, 32768 + 0);
  STAGE_HALF(Bg + 64, 32768 + 16384);
  asm volatile("s_waitcnt vmcnt(0)" ::: "memory");
  BAR();

  for (int t = 0; t < 16; ++t){
    const int cbase = (t & 1) * 32768;
    const int obase = cbase ^ 32768;
    // P1 (k0, m-half0): 8 ds_reads; stage A_k1(t+1)
    LDA_H(0, 0); LDB_ALL(0);
    if (t < 15) STAGE_HALF(Ag + (t+1)*64 + 32, obase + 8192);
    BAR();
    WAIT_LGKM();
    MFMA_Q(0);
    BAR();
    // P2 (k0, m-half1): 4 ds_reads (B held); stage B_k1(t+1)
    LDA_H(0, 1);
    if (t < 15) STAGE_HALF(Bg + (t+1)*64 + 32, obase + 24576);
    BAR();
    WAIT_LGKM();
    MFMA_Q(1);
    if (t < 15) { asm volatile("s_waitcnt vmcnt(6)" ::: "memory"); }
    else        { asm volatile("s_waitcnt vmcnt(0)" ::: "memory"); }
    BAR();
    // P3 (k1, m-half0): 8 ds_reads; stage A_k0(t+2)
    LDA_H(1, 0); LDB_ALL(1);
    if (t < 14) STAGE_HALF(Ag + (t+2)*64, cbase + 0);
    BAR();
    WAIT_LGKM();
    MFMA_Q(0);
    BAR();
    // P4 (k1, m-half1): 4 ds_reads; stage B_k0(t+2)
    LDA_H(1, 1);
    if (t < 14) STAGE_HALF(Bg + (t+2)*64, cbase + 16384);
    BAR();
    WAIT_LGKM();
    MFMA_Q(1);
    if (t < 14) { asm volatile("s_waitcnt vmcnt(6)" ::: "memory"); }
    else        { asm volatile("s_waitcnt vmcnt(0)" ::: "memory"); }
    BAR();
  }

  // ---- epilogue: stage C tile (256x256 bf16 = 128KB) into LDS (32B-XOR
  // swizzle), fused per-chunk scan carries, coalesced 16B/lane Y stores.
  #pragma unroll
  for (int mi = 0; mi < 8; ++mi){
    #pragma unroll
    for (int j = 0; j < 4; ++j){
      #pragma unroll
      for (int q = 0; q < 4; ++q){
        int row = wm*128 + mi*16 + (lane >> 4)*4 + q;
        int col = wn*64 + j*16 + rsel;
        int byte = row*512 + col*2;
        byte ^= ((row >> 2) & 3) << 5;
        *(ushort*)((char*)lds + byte) = f2bf(acc[mi][j][q]);
      }
    }
  }
  __syncthreads();

  // fused scanA: carry over this tile's 4 chunks of 64 t
  {
    const int k_blk = colBase >> 10;
    const int b_blk = rowBase >> 11;
    const int ch0   = (rowBase & 2047) >> 6;
    const int d0    = colBase & 1023;
    const float p   = sigm(dlog[k_blk]);
    #pragma unroll
    for (int s = 0; s < 2; ++s){
      int task = tid + s*512;
      int col = task & 255, ch = task >> 8;     // 256 cols x 4 chunks
      float a = 0.f;
      for (int i = 0; i < 64; ++i){
        int row = ch*64 + i;
        int byte = row*512 + col*2;
        byte ^= ((row >> 2) & 3) << 5;
        a = p * a + bf2f(*(const ushort*)((char*)lds + byte));
      }
      carry[(size_t)((b_blk*Kk + k_blk)*NCH + ch0 + ch) * Dd + d0 + col] = a;
    }
  }

  // coalesced Y write: 16B per lane
  #pragma unroll
  for (int j = 0; j < 16; ++j){
    int idx = tid + j*512;            // 0..8191
    int r = idx >> 5, c8 = idx & 31;
    int byte = r*512 + c8*16;
    byte ^= ((r >> 2) & 3) << 5;
    f32x4 v = *(const f32x4*)((char*)lds + byte);
    *(f32x4*)&C[(size_t)(rowBase + r) * Ee + colBase + c8*8] = v;
  }
}

// ---------------- wave-per-output dot kernels (fp32) ------------------------
__global__ __launch_bounds__(256) void k_z0(const float* __restrict__ Wout,
                                            const float* __restrict__ s0,
                                            float* __restrict__ z0){
  int gid  = blockIdx.x * 4 + (threadIdx.x >> 6);
  int lane = threadIdx.x & 63;
  int d = gid & 1023, k = (gid >> 10) & 3, b = gid >> 12;
  const float* wrow = Wout + (size_t)d * Ee + k * Dd;
  const float* sv   = s0 + ((size_t)(b*Kk + k) << 10);
  float s = 0.f;
  #pragma unroll
  for (int j = 0; j < 16; ++j) s += wrow[lane + j*64] * sv[lane + j*64];
  for (int off = 32; off; off >>= 1) s += __shfl_down(s, off);
  if (lane == 0) z0[gid] = s;
}

__global__ __launch_bounds__(256) void k_cterm(const float* __restrict__ Wout,
                                               const float* __restrict__ b_in,
                                               float* __restrict__ cterm){
  int gid  = blockIdx.x * 4 + (threadIdx.x >> 6);
  int lane = threadIdx.x & 63;
  int d = gid & 1023, k = gid >> 10;
  const float* wrow = Wout + (size_t)d * Ee + k * Dd;
  const float* bv   = b_in + k * Dd;
  float s = 0.f;
  #pragma unroll
  for (int j = 0; j < 16; ++j) s += wrow[lane + j*64] * bv[lane + j*64];
  for (int off = 32; off; off >>= 1) s += __shfl_down(s, off);
  if (lane == 0) cterm[gid] = s;
}

__global__ __launch_bounds__(256) void k_scanInc(const float* __restrict__ carry,
                                                 const float* __restrict__ z0,
                                                 const float* __restrict__ dlog,
                                                 float* __restrict__ incoming){
  int idx = blockIdx.x * 256 + threadIdx.x;
  int k = (idx >> 10) & 3;
  int bk = idx >> 10, d = idx & 1023;
  float p  = sigm(dlog[k]);
  float dL = powf(p, (float)LCH);
  float inc = z0[idx];
  for (int c = 0; c < NCH; ++c){
    size_t o = ((size_t)(bk * NCH + c)) * Dd + d;
    incoming[o] = inc;
    inc = dL * inc + carry[o];
  }
}

__global__ __launch_bounds__(256) void k_scanB(const ushort* __restrict__ Y,
                                               const float* __restrict__ incoming,
                                               const float* __restrict__ dlog,
                                               const float* __restrict__ b_out,
                                               const float* __restrict__ cterm,
                                               float* __restrict__ g){
  int x = blockIdx.x;
  int d = blockIdx.y * 256 + threadIdx.x;
  int c = x & 31, b = x >> 5;
  float p[4], z[4], ct[4], pw[4];
  #pragma unroll
  for (int k = 0; k < 4; ++k){
    p[k]  = sigm(dlog[k]);
    z[k]  = incoming[((size_t)(((b*Kk + k))*NCH + c)) * Dd + d];
    float omp = fmaxf(1.0f - p[k], 1e-30f);
    ct[k] = cterm[k * Dd + d] / omp;
    pw[k] = powf(p[k], (float)(c * LCH + 1));
  }
  float bo = b_out[d];
  size_t ybase = ((size_t)(b*Tt + c*LCH)) * Ee + d;
  size_t gbase = ((size_t)(b*Tt + c*LCH)) * Dd + d;
  for (int i = 0; i < LCH; ++i){
    float acc = bo;
    #pragma unroll
    for (int k = 0; k < 4; ++k){
      z[k] = p[k] * z[k] + bf2f(Y[ybase + (size_t)k * Dd]);
      acc += z[k] + ct[k] * (1.0f - pw[k]);
      pw[k] *= p[k];
    }
    g[gbase] = acc;
    ybase += Ee; gbase += Dd;
  }
}

// ---------------- v path (+ fused u -> bf16 conversion) ---------------------
__global__ __launch_bounds__(256) void k_prep(const float* __restrict__ u,
                                              const float* __restrict__ dlog,
                                              float* __restrict__ vpart,
                                              ushort* __restrict__ U_bf){
  int x = blockIdx.x;                    // b*NCH + c
  int d = blockIdx.y * 256 + threadIdx.x;
  int c = x & 31, b = x >> 5;
  float p[4], a[4] = {0.f, 0.f, 0.f, 0.f};
  #pragma unroll
  for (int k = 0; k < 4; ++k) p[k] = sigm(dlog[k]);
  size_t ub = ((size_t)(b*Tt + c*LCH)) * Dd + d;
  for (int i = 0; i < LCH; ++i){
    float uv = u[ub];
    U_bf[ub] = f2bf(uv);
    #pragma unroll
    for (int k = 0; k < 4; ++k) a[k] = p[k] * a[k] + uv;
    ub += Dd;
  }
  #pragma unroll
  for (int k = 0; k < 4; ++k)
    vpart[(((size_t)x) * Kk + k) * Dd + d] = a[k];
}

__global__ __launch_bounds__(256) void k_vcomb(const float* __restrict__ vpart,
                                               const float* __restrict__ dlog,
                                               float* __restrict__ vfull){
  int idx = blockIdx.x * 256 + threadIdx.x;
  int k = (idx >> 10) & 3, b = idx >> 12, d = idx & 1023;
  float p  = sigm(dlog[k]);
  float dL = powf(p, (float)LCH);
  float v = 0.f;
  for (int c = 0; c < NCH; ++c)
    v = dL * v + vpart[(((size_t)(b*NCH + c)) * Kk + k) * Dd + d];
  vfull[idx] = v;
}

__global__ __launch_bounds__(256) void k_slast(const float* __restrict__ W_in,
                                               const float* __restrict__ vfull,
                                               const float* __restrict__ s0,
                                               const float* __restrict__ b_in,
                                               const float* __restrict__ dlog,
                                               float* __restrict__ out){
  int gid  = blockIdx.x * 4 + (threadIdx.x >> 6);
  int lane = threadIdx.x & 63;
  int d = gid & 1023, k = (gid >> 10) & 3, b = gid >> 12;
  const float* wrow = W_in + (size_t)(k*Dd + d) * Dd;
  const float* vv   = vfull + ((size_t)(b*Kk + k) << 10);
  float s = 0.f;
  #pragma unroll
  for (int j = 0; j < 16; ++j) s += wrow[lane + j*64] * vv[lane + j*64];
  for (int off = 32; off; off >>= 1) s += __shfl_down(s, off);
  if (lane == 0){
    float p  = sigm(dlog[k]);
    float pT = powf(p, (float)Tt);
    float omp = 1.0f - p;
    float geo = (omp < 1e-12f) ? (float)Tt : (1.0f - pT) / omp;
    out[gid] = pT * s0[gid] + s + b_in[k*Dd + d] * geo;
  }
}

// ---------------------------------------------------------------------------
extern "C" void kernel_launch(void* const* d_in, const int* in_sizes, int n_in,
                              void* d_out, int out_size, void* d_ws, size_t ws_size,
                              hipStream_t stream){
  const float* u     = (const float*)d_in[0];
  const float* s0    = (const float*)d_in[1];
  const float* W_in  = (const float*)d_in[2];
  const float* b_in  = (const float*)d_in[3];
  const float* W_out = (const float*)d_in[4];
  const float* b_out = (const float*)d_in[5];
  const float* dlog  = (const float*)d_in[6];

  float* g_out     = (float*)d_out;                      // B*T*D
  float* slast_out = g_out + (size_t)BT * Dd;            // B*K*D

  char* ws = (char*)d_ws;
  if (ws_size < 115490816ull) return;
  ushort* U_bf    = (ushort*)(ws);                       // 16 MB
  ushort* WinT    = (ushort*)(ws + 16777216);            //  8 MB
  ushort* Wout_bf = (ushort*)(ws + 25165824);            //  8 MB
  ushort* Mcat    = (ushort*)(ws + 33554432);            //  8 MB
  ushort* Y       = (ushort*)(ws + 41943040);            // 64 MB
  float*  carry   = (float*)(ws + 109051904);            //  2 MB
  float*  incoming= (float*)(ws + 111149056);            //  2 MB
  float*  z0buf   = (float*)(ws + 113246208);            // 64 KB
  float*  cterm   = (float*)(ws + 113311744);            // 16 KB
  float*  vpart   = (float*)(ws + 113328128);            //  2 MB
  float*  vfull   = (float*)(ws + 115425280);            // 64 KB

  // prep: u -> U_bf (fused) + vpart; weight converts
  k_prep<<<dim3(128, 4), 256, 0, stream>>>(u, dlog, vpart, U_bf);
  k_f2bf4<<<4096, 256, 0, stream>>>((const float4*)W_out, (ushort4*)Wout_bf, Dd*Ee/4);
  k_transpose<<<dim3(32, 128), dim3(32, 8), 0, stream>>>(W_in, WinT);

  // Mcat[(k,d), d'] = sum_j Wout[d, kD+j] * WinT[d', kD+j]
  gemm_nt<<<dim3(8, 8, 4), 256, 0, stream>>>(Wout_bf, WinT, Mcat,
                                             1024, Ee, Ee, Dd,
                                             1024L, 1024L, 1048576L);
  // Y = U @ Mcat^T, balanced 4-phase 256^2, fused chunk-carry epilogue
  gemm_big<<<512, 512, 0, stream>>>(U_bf, Mcat, Y, dlog, carry);

  // scan-init terms
  k_z0<<<4096, 256, 0, stream>>>(W_out, s0, z0buf);
  k_cterm<<<1024, 256, 0, stream>>>(W_out, b_in, cterm);

  // cross-chunk scan + apply
  k_scanInc<<<64, 256, 0, stream>>>(carry, z0buf, dlog, incoming);
  k_scanB<<<dim3(128, 4), 256, 0, stream>>>(Y, incoming, dlog, b_out, cterm, g_out);

  // s_last path
  k_vcomb<<<64, 256, 0, stream>>>(vpart, dlog, vfull);
  k_slast<<<4096, 256, 0, stream>>>(W_in, vfull, s0, b_in, dlog, slast_out);
}

// Round 8
// 169.441 us; speedup vs baseline: 1.1992x; 1.0077x over previous
//
#include <hip/hip_runtime.h>

// ---------------------------------------------------------------------------
// StateBank: g = W_out @ scan(W_in @ u), restructured as
//   M_k = W_out_k @ W_in_k  (composite, k=0..3, each 1024x1024)
//   Y[b,t,(k,d)] = sum_d' M_k[d,d'] u[b,t,d']       (one 8192x4096x1024 GEMM)
//   z_k[b,t,d] = decay_k z_k[b,t-1,d] + Y[..]       (chunked parallel scan)
//   g[b,t,d] = b_out[d] + sum_k z_k + closed-form b_in/s0 terms
//   s_last[b,k,d] = decay^T s0 + W_in_k @ v_k[b] + b_in geom term
// Big GEMM: 256x256, BK=64, 8 waves, 1 block/CU (128KB LDS). Free-running
// K-tile interior (NO per-phase barriers): each wave issues its 24 ds_reads
// + 64 MFMAs, compiler schedules with fine lgkmcnt; LDS pipe overlaps MFMA
// pipe ACROSS waves. Only 2 barriers/K-tile: lgkmcnt(0)+bar (read-done
// before buffer overwrite), stage+vmcnt(8)+bar (prefetch landed, counted
// not drained). Region XCD map. Fused carry epilogue.
// ---------------------------------------------------------------------------

#define Bb 4
#define Tt 2048
#define Dd 1024
#define Kk 4
#define BT (Bb*Tt)          // 8192
#define Ee (Kk*Dd)          // 4096
#define NCH 32              // scan chunks
#define LCH 64              // chunk length (NCH*LCH = T)

typedef __bf16 bf16x8 __attribute__((ext_vector_type(8)));
typedef float  f32x4  __attribute__((ext_vector_type(4)));

__device__ __forceinline__ float bf2f(ushort u){
  union { unsigned int i; float f; } x; x.i = ((unsigned int)u) << 16; return x.f;
}
__device__ __forceinline__ ushort f2bf(float f){
  union { unsigned int i; float f; } x; x.f = f;
  unsigned int i = x.i;
  return (ushort)((i + 0x7FFFu + ((i >> 16) & 1u)) >> 16);   // RNE
}
__device__ __forceinline__ float sigm(float x){ return 1.0f / (1.0f + expf(-x)); }

// ---------------- convert f32 -> bf16 (vectorized) ----------------
__global__ __launch_bounds__(256) void k_f2bf4(const float4* __restrict__ in,
                                               ushort4* __restrict__ out, int n4){
  int i = blockIdx.x * 256 + threadIdx.x;
  if (i < n4){
    float4 v = in[i];
    ushort4 o; o.x = f2bf(v.x); o.y = f2bf(v.y); o.z = f2bf(v.z); o.w = f2bf(v.w);
    out[i] = o;
  }
}

// ---------------- transpose W_in (4096x1024 f32) -> WinT (1024x4096 bf16) ---
__global__ __launch_bounds__(256) void k_transpose(const float* __restrict__ in,
                                                   ushort* __restrict__ out){
  __shared__ float tile[32][33];
  int tx = threadIdx.x, ty = threadIdx.y;          // 32 x 8
  int c0 = blockIdx.x * 32, r0 = blockIdx.y * 32;  // cols of in, rows of in
  #pragma unroll
  for (int j = 0; j < 4; ++j)
    tile[ty + j*8][tx] = in[(size_t)(r0 + ty + j*8) * Dd + c0 + tx];
  __syncthreads();
  #pragma unroll
  for (int j = 0; j < 4; ++j)
    out[(size_t)(c0 + ty + j*8) * Ee + r0 + tx] = f2bf(tile[tx][ty + j*8]);
}

// ---------------- small NT GEMM (m97 structure) for Mcat --------------------
__global__ __launch_bounds__(256) void gemm_nt(const ushort* __restrict__ A,
                                               const ushort* __restrict__ B,
                                               ushort* __restrict__ C,
                                               int Kred, int lda, int ldb, int ldc,
                                               long aBatch, long bBatch, long cBatch){
  __shared__ ushort As[128 * 32];
  __shared__ ushort Bs[128 * 32];
  A += (long)blockIdx.z * aBatch;
  B += (long)blockIdx.z * bBatch;
  C += (long)blockIdx.z * cBatch;
  const int tid  = threadIdx.x;
  const int lane = tid & 63;
  const int w    = tid >> 6;
  const int wr   = w >> 1, wc = w & 1;
  const int rowBase = blockIdx.x * 128;
  const int colBase = blockIdx.y * 128;

  f32x4 acc[4][4] = {};
  const int krow = (lane >> 4) * 8;
  const int rsel = lane & 15;

  for (int kk = 0; kk < Kred; kk += 32){
    __syncthreads();
    #pragma unroll
    for (int i = 0; i < 2; ++i){
      int c  = i * 256 + tid;
      int r  = c >> 2;
      int c8 = (c & 3) * 8;
      const ushort* ga = A + (size_t)(rowBase + r) * lda + kk + c8;
      const ushort* gb = B + (size_t)(colBase + r) * ldb + kk + c8;
      __builtin_amdgcn_global_load_lds((const __attribute__((address_space(1))) void*)ga,
                                       (__attribute__((address_space(3))) void*)&As[c * 8],
                                       16, 0, 0);
      __builtin_amdgcn_global_load_lds((const __attribute__((address_space(1))) void*)gb,
                                       (__attribute__((address_space(3))) void*)&Bs[c * 8],
                                       16, 0, 0);
    }
    asm volatile("s_waitcnt vmcnt(0)" ::: "memory");
    __syncthreads();

    bf16x8 Af[4], Bf[4];
    #pragma unroll
    for (int mi = 0; mi < 4; ++mi)
      Af[mi] = *(const bf16x8*)&As[(wr*64 + mi*16 + rsel) * 32 + krow];
    #pragma unroll
    for (int ni = 0; ni < 4; ++ni)
      Bf[ni] = *(const bf16x8*)&Bs[(wc*64 + ni*16 + rsel) * 32 + krow];
    #pragma unroll
    for (int mi = 0; mi < 4; ++mi)
      #pragma unroll
      for (int ni = 0; ni < 4; ++ni)
        acc[mi][ni] = __builtin_amdgcn_mfma_f32_16x16x32_bf16(Af[mi], Bf[ni], acc[mi][ni], 0, 0, 0);
  }

  #pragma unroll
  for (int mi = 0; mi < 4; ++mi){
    #pragma unroll
    for (int ni = 0; ni < 4; ++ni){
      int r0 = rowBase + wr*64 + mi*16 + (lane >> 4) * 4;
      int c0 = colBase + wc*64 + ni*16 + (lane & 15);
      #pragma unroll
      for (int q = 0; q < 4; ++q)
        C[(size_t)(r0 + q) * ldc + c0] = f2bf(acc[mi][ni][q]);
    }
  }
}

// ---------------- big GEMM: Y[8192,4096] = U[8192,1024] @ Mcat[4096,1024]^T -
// LDS buf: A_k0 @0, A_k1 @8192, B_k0 @16384, B_k1 @24576 (ushort offsets).
#define STAGE_HALF(GB, LOFF)                                                   \
  { _Pragma("unroll")                                                          \
    for (int i_ = 0; i_ < 2; ++i_){                                            \
      int c_ = tid + i_*512;                                                   \
      int row_ = c_ >> 2;                                                      \
      int ss_ = (c_ & 3) ^ ((row_ >> 2) & 3);                                  \
      const ushort* g_ = (GB) + (size_t)row_ * 1024 + ss_ * 8;                 \
      __builtin_amdgcn_global_load_lds(                                        \
        (const __attribute__((address_space(1))) void*)g_,                     \
        (__attribute__((address_space(3))) void*)&lds[(LOFF) + c_*8],          \
        16, 0, 0);                                                             \
    } }

#define LOAD_A4(DST, KH, MH)                                                   \
  { _Pragma("unroll")                                                          \
    for (int mi_ = 0; mi_ < 4; ++mi_){                                         \
      int r_ = wm*128 + (MH)*64 + mi_*16 + rsel;                               \
      int uo_ = r_*32 + kq*8;                                                  \
      uo_ ^= ((uo_ >> 7) & 3) << 3;                                            \
      DST[mi_] = *(const bf16x8*)&lds[cbase + (KH)*8192 + uo_];                \
    } }

#define LOAD_B4(DST, KH)                                                       \
  { _Pragma("unroll")                                                          \
    for (int ni_ = 0; ni_ < 4; ++ni_){                                         \
      int r_ = wn*64 + ni_*16 + rsel;                                          \
      int uo_ = r_*32 + kq*8;                                                  \
      uo_ ^= ((uo_ >> 7) & 3) << 3;                                            \
      DST[ni_] = *(const bf16x8*)&lds[cbase + 16384 + (KH)*8192 + uo_];        \
    } }

#define MFMA16(MH, AARR, BARR)                                                 \
  { _Pragma("unroll")                                                          \
    for (int mi_ = 0; mi_ < 4; ++mi_)                                          \
      { _Pragma("unroll")                                                      \
        for (int ni_ = 0; ni_ < 4; ++ni_)                                      \
          acc[(MH)*4+mi_][ni_] = __builtin_amdgcn_mfma_f32_16x16x32_bf16(      \
              AARR[mi_], BARR[ni_], acc[(MH)*4+mi_][ni_], 0, 0, 0); } }

#define BAR() __builtin_amdgcn_s_barrier()

__global__ __launch_bounds__(512, 2) void gemm_big(const ushort* __restrict__ A,
                                                   const ushort* __restrict__ B,
                                                   ushort* __restrict__ C,
                                                   const float* __restrict__ dlog,
                                                   float* __restrict__ carry){
  __shared__ ushort lds[65536];       // 128 KB -> 1 block/CU
  const int tid  = threadIdx.x;
  const int lane = tid & 63;
  const int w    = tid >> 6;          // 0..7
  const int wm   = w >> 2;            // 2 M-waves
  const int wn   = w & 3;             // 4 N-waves
  const int rsel = lane & 15;
  const int kq   = lane >> 4;

  // XCD region map: 8Mx8N tile region per XCD (per-XCD footprint 4+4 MB).
  int bid = blockIdx.x;
  int xcd = bid & 7, rr = bid >> 3;   // rr in 0..63
  const int rowBase = (((xcd >> 1) << 3) + (rr & 7)) * 256;   // 32 M-tiles
  const int colBase = (((xcd & 1) << 3) + (rr >> 3)) * 256;   // 16 N-tiles

  const ushort* Ag = A + (size_t)rowBase * 1024;
  const ushort* Bg = B + (size_t)colBase * 1024;

  f32x4 acc[8][4] = {};

  // prologue: stage tile0 -> buf0 (8 loads/thread), tile1 -> buf1 (8);
  // wait tile0 landed (8 still outstanding), barrier.
  STAGE_HALF(Ag +  0, 0);
  STAGE_HALF(Bg +  0, 16384);
  STAGE_HALF(Ag + 32, 8192);
  STAGE_HALF(Bg + 32, 24576);
  STAGE_HALF(Ag + 64, 32768 + 0);
  STAGE_HALF(Bg + 64, 32768 + 16384);
  STAGE_HALF(Ag + 96, 32768 + 8192);
  STAGE_HALF(Bg + 96, 32768 + 24576);
  asm volatile("s_waitcnt vmcnt(8)" ::: "memory");
  BAR();

  for (int t = 0; t < 16; ++t){
    const int cbase = (t & 1) * 32768;
    bf16x8 am0[4], am1[4], bf0[4];
    // k-half 0: 12 ds_reads + 32 MFMA (compiler interleaves, fine lgkmcnt)
    LOAD_A4(am0, 0, 0); LOAD_B4(bf0, 0); LOAD_A4(am1, 0, 1);
    MFMA16(0, am0, bf0);
    MFMA16(1, am1, bf0);
    // k-half 1
    LOAD_A4(am0, 1, 0); LOAD_B4(bf0, 1); LOAD_A4(am1, 1, 1);
    MFMA16(0, am0, bf0);
    MFMA16(1, am1, bf0);
    // all this wave's reads of buf(cbase) complete before signaling
    asm volatile("s_waitcnt lgkmcnt(0)" ::: "memory");
    BAR();
    // overwrite buf(cbase) with tile t+2; ensure tile t+1 landed (counted)
    if (t < 14){
      STAGE_HALF(Ag + (t+2)*64,      cbase + 0);
      STAGE_HALF(Bg + (t+2)*64,      cbase + 16384);
      STAGE_HALF(Ag + (t+2)*64 + 32, cbase + 8192);
      STAGE_HALF(Bg + (t+2)*64 + 32, cbase + 24576);
      asm volatile("s_waitcnt vmcnt(8)" ::: "memory");
    } else {
      asm volatile("s_waitcnt vmcnt(0)" ::: "memory");
    }
    BAR();
  }

  // ---- epilogue: stage C tile (256x256 bf16 = 128KB) into LDS (32B-XOR
  // swizzle), fused per-chunk scan carries, coalesced 16B/lane Y stores.
  #pragma unroll
  for (int mi = 0; mi < 8; ++mi){
    #pragma unroll
    for (int j = 0; j < 4; ++j){
      #pragma unroll
      for (int q = 0; q < 4; ++q){
        int row = wm*128 + mi*16 + (lane >> 4)*4 + q;
        int col = wn*64 + j*16 + rsel;
        int byte = row*512 + col*2;
        byte ^= ((row >> 2) & 3) << 5;
        *(ushort*)((char*)lds + byte) = f2bf(acc[mi][j][q]);
      }
    }
  }
  __syncthreads();

  // fused scanA: carry over this tile's 4 chunks of 64 t
  {
    const int k_blk = colBase >> 10;
    const int b_blk = rowBase >> 11;
    const int ch0   = (rowBase & 2047) >> 6;
    const int d0    = colBase & 1023;
    const float p   = sigm(dlog[k_blk]);
    #pragma unroll
    for (int s = 0; s < 2; ++s){
      int task = tid + s*512;
      int col = task & 255, ch = task >> 8;     // 256 cols x 4 chunks
      float a = 0.f;
      for (int i = 0; i < 64; ++i){
        int row = ch*64 + i;
        int byte = row*512 + col*2;
        byte ^= ((row >> 2) & 3) << 5;
        a = p * a + bf2f(*(const ushort*)((char*)lds + byte));
      }
      carry[(size_t)((b_blk*Kk + k_blk)*NCH + ch0 + ch) * Dd + d0 + col] = a;
    }
  }

  // coalesced Y write: 16B per lane
  #pragma unroll
  for (int j = 0; j < 16; ++j){
    int idx = tid + j*512;            // 0..8191
    int r = idx >> 5, c8 = idx & 31;
    int byte = r*512 + c8*16;
    byte ^= ((r >> 2) & 3) << 5;
    f32x4 v = *(const f32x4*)((char*)lds + byte);
    *(f32x4*)&C[(size_t)(rowBase + r) * Ee + colBase + c8*8] = v;
  }
}

// ---------------- wave-per-output dot kernels (fp32) ------------------------
__global__ __launch_bounds__(256) void k_z0(const float* __restrict__ Wout,
                                            const float* __restrict__ s0,
                                            float* __restrict__ z0){
  int gid  = blockIdx.x * 4 + (threadIdx.x >> 6);
  int lane = threadIdx.x & 63;
  int d = gid & 1023, k = (gid >> 10) & 3, b = gid >> 12;
  const float* wrow = Wout + (size_t)d * Ee + k * Dd;
  const float* sv   = s0 + ((size_t)(b*Kk + k) << 10);
  float s = 0.f;
  #pragma unroll
  for (int j = 0; j < 16; ++j) s += wrow[lane + j*64] * sv[lane + j*64];
  for (int off = 32; off; off >>= 1) s += __shfl_down(s, off);
  if (lane == 0) z0[gid] = s;
}

__global__ __launch_bounds__(256) void k_cterm(const float* __restrict__ Wout,
                                               const float* __restrict__ b_in,
                                               float* __restrict__ cterm){
  int gid  = blockIdx.x * 4 + (threadIdx.x >> 6);
  int lane = threadIdx.x & 63;
  int d = gid & 1023, k = gid >> 10;
  const float* wrow = Wout + (size_t)d * Ee + k * Dd;
  const float* bv   = b_in + k * Dd;
  float s = 0.f;
  #pragma unroll
  for (int j = 0; j < 16; ++j) s += wrow[lane + j*64] * bv[lane + j*64];
  for (int off = 32; off; off >>= 1) s += __shfl_down(s, off);
  if (lane == 0) cterm[gid] = s;
}

__global__ __launch_bounds__(256) void k_scanInc(const float* __restrict__ carry,
                                                 const float* __restrict__ z0,
                                                 const float* __restrict__ dlog,
                                                 float* __restrict__ incoming){
  int idx = blockIdx.x * 256 + threadIdx.x;
  int k = (idx >> 10) & 3;
  int bk = idx >> 10, d = idx & 1023;
  float p  = sigm(dlog[k]);
  float dL = powf(p, (float)LCH);
  float inc = z0[idx];
  for (int c = 0; c < NCH; ++c){
    size_t o = ((size_t)(bk * NCH + c)) * Dd + d;
    incoming[o] = inc;
    inc = dL * inc + carry[o];
  }
}

__global__ __launch_bounds__(256) void k_scanB(const ushort* __restrict__ Y,
                                               const float* __restrict__ incoming,
                                               const float* __restrict__ dlog,
                                               const float* __restrict__ b_out,
                                               const float* __restrict__ cterm,
                                               float* __restrict__ g){
  int x = blockIdx.x;
  int d = blockIdx.y * 256 + threadIdx.x;
  int c = x & 31, b = x >> 5;
  float p[4], z[4], ct[4], pw[4];
  #pragma unroll
  for (int k = 0; k < 4; ++k){
    p[k]  = sigm(dlog[k]);
    z[k]  = incoming[((size_t)(((b*Kk + k))*NCH + c)) * Dd + d];
    float omp = fmaxf(1.0f - p[k], 1e-30f);
    ct[k] = cterm[k * Dd + d] / omp;
    pw[k] = powf(p[k], (float)(c * LCH + 1));
  }
  float bo = b_out[d];
  size_t ybase = ((size_t)(b*Tt + c*LCH)) * Ee + d;
  size_t gbase = ((size_t)(b*Tt + c*LCH)) * Dd + d;
  for (int i = 0; i < LCH; ++i){
    float acc = bo;
    #pragma unroll
    for (int k = 0; k < 4; ++k){
      z[k] = p[k] * z[k] + bf2f(Y[ybase + (size_t)k * Dd]);
      acc += z[k] + ct[k] * (1.0f - pw[k]);
      pw[k] *= p[k];
    }
    g[gbase] = acc;
    ybase += Ee; gbase += Dd;
  }
}

// ---------------- v path (+ fused u -> bf16 conversion) ---------------------
__global__ __launch_bounds__(256) void k_prep(const float* __restrict__ u,
                                              const float* __restrict__ dlog,
                                              float* __restrict__ vpart,
                                              ushort* __restrict__ U_bf){
  int x = blockIdx.x;                    // b*NCH + c
  int d = blockIdx.y * 256 + threadIdx.x;
  int c = x & 31, b = x >> 5;
  float p[4], a[4] = {0.f, 0.f, 0.f, 0.f};
  #pragma unroll
  for (int k = 0; k < 4; ++k) p[k] = sigm(dlog[k]);
  size_t ub = ((size_t)(b*Tt + c*LCH)) * Dd + d;
  for (int i = 0; i < LCH; ++i){
    float uv = u[ub];
    U_bf[ub] = f2bf(uv);
    #pragma unroll
    for (int k = 0; k < 4; ++k) a[k] = p[k] * a[k] + uv;
    ub += Dd;
  }
  #pragma unroll
  for (int k = 0; k < 4; ++k)
    vpart[(((size_t)x) * Kk + k) * Dd + d] = a[k];
}

__global__ __launch_bounds__(256) void k_vcomb(const float* __restrict__ vpart,
                                               const float* __restrict__ dlog,
                                               float* __restrict__ vfull){
  int idx = blockIdx.x * 256 + threadIdx.x;
  int k = (idx >> 10) & 3, b = idx >> 12, d = idx & 1023;
  float p  = sigm(dlog[k]);
  float dL = powf(p, (float)LCH);
  float v = 0.f;
  for (int c = 0; c < NCH; ++c)
    v = dL * v + vpart[(((size_t)(b*NCH + c)) * Kk + k) * Dd + d];
  vfull[idx] = v;
}

__global__ __launch_bounds__(256) void k_slast(const float* __restrict__ W_in,
                                               const float* __restrict__ vfull,
                                               const float* __restrict__ s0,
                                               const float* __restrict__ b_in,
                                               const float* __restrict__ dlog,
                                               float* __restrict__ out){
  int gid  = blockIdx.x * 4 + (threadIdx.x >> 6);
  int lane = threadIdx.x & 63;
  int d = gid & 1023, k = (gid >> 10) & 3, b = gid >> 12;
  const float* wrow = W_in + (size_t)(k*Dd + d) * Dd;
  const float* vv   = vfull + ((size_t)(b*Kk + k) << 10);
  float s = 0.f;
  #pragma unroll
  for (int j = 0; j < 16; ++j) s += wrow[lane + j*64] * vv[lane + j*64];
  for (int off = 32; off; off >>= 1) s += __shfl_down(s, off);
  if (lane == 0){
    float p  = sigm(dlog[k]);
    float pT = powf(p, (float)Tt);
    float omp = 1.0f - p;
    float geo = (omp < 1e-12f) ? (float)Tt : (1.0f - pT) / omp;
    out[gid] = pT * s0[gid] + s + b_in[k*Dd + d] * geo;
  }
}

// ---------------------------------------------------------------------------
extern "C" void kernel_launch(void* const* d_in, const int* in_sizes, int n_in,
                              void* d_out, int out_size, void* d_ws, size_t ws_size,
                              hipStream_t stream){
  const float* u     = (const float*)d_in[0];
  const float* s0    = (const float*)d_in[1];
  const float* W_in  = (const float*)d_in[2];
  const float* b_in  = (const float*)d_in[3];
  const float* W_out = (const float*)d_in[4];
  const float* b_out = (const float*)d_in[5];
  const float* dlog  = (const float*)d_in[6];

  float* g_out     = (float*)d_out;                      // B*T*D
  float* slast_out = g_out + (size_t)BT * Dd;            // B*K*D

  char* ws = (char*)d_ws;
  if (ws_size < 115490816ull) return;
  ushort* U_bf    = (ushort*)(ws);                       // 16 MB
  ushort* WinT    = (ushort*)(ws + 16777216);            //  8 MB
  ushort* Wout_bf = (ushort*)(ws + 25165824);            //  8 MB
  ushort* Mcat    = (ushort*)(ws + 33554432);            //  8 MB
  ushort* Y       = (ushort*)(ws + 41943040);            // 64 MB
  float*  carry   = (float*)(ws + 109051904);            //  2 MB
  float*  incoming= (float*)(ws + 111149056);            //  2 MB
  float*  z0buf   = (float*)(ws + 113246208);            // 64 KB
  float*  cterm   = (float*)(ws + 113311744);            // 16 KB
  float*  vpart   = (float*)(ws + 113328128);            //  2 MB
  float*  vfull   = (float*)(ws + 115425280);            // 64 KB

  // prep: u -> U_bf (fused) + vpart; weight converts
  k_prep<<<dim3(128, 4), 256, 0, stream>>>(u, dlog, vpart, U_bf);
  k_f2bf4<<<4096, 256, 0, stream>>>((const float4*)W_out, (ushort4*)Wout_bf, Dd*Ee/4);
  k_transpose<<<dim3(32, 128), dim3(32, 8), 0, stream>>>(W_in, WinT);

  // Mcat[(k,d), d'] = sum_j Wout[d, kD+j] * WinT[d', kD+j]
  gemm_nt<<<dim3(8, 8, 4), 256, 0, stream>>>(Wout_bf, WinT, Mcat,
                                             1024, Ee, Ee, Dd,
                                             1024L, 1024L, 1048576L);
  // Y = U @ Mcat^T, free-running 256^2, fused chunk-carry epilogue
  gemm_big<<<512, 512, 0, stream>>>(U_bf, Mcat, Y, dlog, carry);

  // scan-init terms
  k_z0<<<4096, 256, 0, stream>>>(W_out, s0, z0buf);
  k_cterm<<<1024, 256, 0, stream>>>(W_out, b_in, cterm);

  // cross-chunk scan + apply
  k_scanInc<<<64, 256, 0, stream>>>(carry, z0buf, dlog, incoming);
  k_scanB<<<dim3(128, 4), 256, 0, stream>>>(Y, incoming, dlog, b_out, cterm, g_out);

  // s_last path
  k_vcomb<<<64, 256, 0, stream>>>(vpart, dlog, vfull);
  k_slast<<<4096, 256, 0, stream>>>(W_in, vfull, s0, b_in, dlog, slast_out);
}